// Round 3
// baseline (336.580 us; speedup 1.0000x reference)
//
#include <hip/hip_runtime.h>
#include <hip/hip_bf16.h>
#include <cstddef>
#include <cstdint>

// Problem constants
#define BB 4
#define CC 512
#define TT 2048
#define NN 4096
#define HH 4
// d = CC/HH = 128

constexpr float KFAC       = 0.04419417382415922f;           // 1/(sqrt(128)*2)
constexpr float INV_S18    = 1.0f / 262144.0f;               // 2^-18 (undo two x512)
constexpr float INV_SCALE2 = 1.0f / (512.0f * 512.0f);

typedef _Float16 f16x8 __attribute__((ext_vector_type(8)));
typedef _Float16 f16x4 __attribute__((ext_vector_type(4)));
typedef float    f32x4 __attribute__((ext_vector_type(4)));

__device__ __forceinline__ void gld16(const void* g, void* s) {
    __builtin_amdgcn_global_load_lds(
        (const __attribute__((address_space(1))) void*)g,
        (__attribute__((address_space(3))) void*)s, 16, 0, 0);
}

struct HL { _Float16 h, l; };
__device__ __forceinline__ HL split512(float x) {
    float v = x * 512.0f;
    _Float16 h = (_Float16)v;
    return { h, (_Float16)(v - (float)h) };
}

// ---------------------------------------------------------------------------
// Prep 1: elementwise split (x512) of cb [N][C] -> cbhi/cblo fp16 [N][C]
// ---------------------------------------------------------------------------
__global__ __launch_bounds__(256) void k_split(
    const float* __restrict__ src, _Float16* __restrict__ hi, _Float16* __restrict__ lo, int n4)
{
    int q = blockIdx.x * 256 + threadIdx.x;
    if (q >= n4) return;
    float4 v = *(const float4*)(src + (size_t)q * 4);
    f16x4 H, L;
    HL a = split512(v.x); H[0] = a.h; L[0] = a.l;
    HL b = split512(v.y); H[1] = b.h; L[1] = b.l;
    HL c = split512(v.z); H[2] = c.h; L[2] = c.l;
    HL d = split512(v.w); H[3] = d.h; L[3] = d.l;
    *(f16x4*)(hi + (size_t)q * 4) = H;
    *(f16x4*)(lo + (size_t)q * 4) = L;
}

// ---------------------------------------------------------------------------
// Prep 2: transpose + split (x512): src fp32 [R][S] -> dst hi/lo fp16 [S][R]
// ---------------------------------------------------------------------------
__device__ __forceinline__ void tsplit_body(
    const float* __restrict__ src, _Float16* __restrict__ hi, _Float16* __restrict__ lo,
    int S, int R, int r0, int s0)
{
    __shared__ float ls[64][65];
    const int tid = threadIdx.x;
    #pragma unroll
    for (int i = 0; i < 4; ++i) {
        int q = tid + i * 256;
        int row = q >> 4, c4 = (q & 15) * 4;
        float4 v = *(const float4*)(src + (size_t)(r0 + row) * S + s0 + c4);
        ls[row][c4] = v.x; ls[row][c4 + 1] = v.y;
        ls[row][c4 + 2] = v.z; ls[row][c4 + 3] = v.w;
    }
    __syncthreads();
    #pragma unroll
    for (int i = 0; i < 2; ++i) {
        int q = tid + i * 256;
        int orow = q >> 3, seg = (q & 7) * 8;
        f16x8 H, L;
        #pragma unroll
        for (int j = 0; j < 8; ++j) {
            HL s = split512(ls[seg + j][orow]);
            H[j] = s.h; L[j] = s.l;
        }
        size_t off = (size_t)(s0 + orow) * R + r0 + seg;
        *(f16x8*)(hi + off) = H;
        *(f16x8*)(lo + off) = L;
    }
}

__global__ __launch_bounds__(256) void k_tsplit(
    const float* __restrict__ src, _Float16* __restrict__ hi, _Float16* __restrict__ lo,
    long sbatch, long dbatch, int S, int R)
{
    src += (size_t)blockIdx.z * sbatch;
    hi  += (size_t)blockIdx.z * dbatch;
    lo  += (size_t)blockIdx.z * dbatch;
    tsplit_body(src, hi, lo, S, R, blockIdx.y * 64, blockIdx.x * 64);
}

__global__ __launch_bounds__(256) void k_tsplit_w(
    const float* __restrict__ w0, const float* __restrict__ w1, const float* __restrict__ w2,
    _Float16* __restrict__ h0, _Float16* __restrict__ h1, _Float16* __restrict__ h2,
    _Float16* __restrict__ l0, _Float16* __restrict__ l1, _Float16* __restrict__ l2)
{
    const int z = blockIdx.z;
    const float* src = z == 0 ? w0 : z == 1 ? w1 : w2;
    _Float16* hi = z == 0 ? h0 : z == 1 ? h1 : h2;
    _Float16* lo = z == 0 ? l0 : z == 1 ? l1 : l2;
    tsplit_body(src, hi, lo, CC, CC, blockIdx.y * 64, blockIdx.x * 64);
}

// ---------------------------------------------------------------------------
// MFMA tile core (projections): 128x128 tile, BK=32, 4 waves, 3-term split.
// ---------------------------------------------------------------------------
#define MFMA_TILE_DECLS                                                       \
    __shared__ __align__(16) _Float16 Ah[128][32];                            \
    __shared__ __align__(16) _Float16 Al[128][32];                            \
    __shared__ __align__(16) _Float16 Bh[128][32];                            \
    __shared__ __align__(16) _Float16 Bl[128][32];                            \
    const int tid  = threadIdx.x;                                             \
    const int w    = tid >> 6;                                                \
    const int l    = tid & 63;                                                \
    const int quad = l >> 4;                                                  \
    const int l15  = l & 15;                                                  \
    const int wm   = (w >> 1) * 64;                                           \
    const int wn   = (w & 1) * 64;                                            \
    const int rA   = l >> 2;                                                  \
    const int cA   = (l & 3) * 8;                                             \
    f32x4 acc[4][4];                                                          \
    _Pragma("unroll") for (int i = 0; i < 4; ++i)                             \
        _Pragma("unroll") for (int j = 0; j < 4; ++j)                         \
            acc[i][j] = (f32x4){0.f, 0.f, 0.f, 0.f};

#define MFMA_TILE_STAGE(pAh, pAl, pBh, pBl, k0, srcStride)                    \
    gld16(pAh + k0,                    &Ah[w * 32][0]);                       \
    gld16(pAh + k0 + 16 * (srcStride), &Ah[w * 32 + 16][0]);                  \
    gld16(pAl + k0,                    &Al[w * 32][0]);                       \
    gld16(pAl + k0 + 16 * (srcStride), &Al[w * 32 + 16][0]);                  \
    gld16(pBh + k0,                    &Bh[w * 32][0]);                       \
    gld16(pBh + k0 + 16 * (srcStride), &Bh[w * 32 + 16][0]);                  \
    gld16(pBl + k0,                    &Bl[w * 32][0]);                       \
    gld16(pBl + k0 + 16 * (srcStride), &Bl[w * 32 + 16][0]);

#define MFMA_TILE_COMPUTE                                                     \
    {                                                                         \
        f16x8 fah[4], fal[4], fbh[4], fbl[4];                                 \
        _Pragma("unroll") for (int i = 0; i < 4; ++i) {                       \
            fah[i] = *(const f16x8*)&Ah[wm + i * 16 + l15][quad * 8];         \
            fal[i] = *(const f16x8*)&Al[wm + i * 16 + l15][quad * 8];         \
            fbh[i] = *(const f16x8*)&Bh[wn + i * 16 + l15][quad * 8];         \
            fbl[i] = *(const f16x8*)&Bl[wn + i * 16 + l15][quad * 8];         \
        }                                                                     \
        _Pragma("unroll") for (int i = 0; i < 4; ++i)                         \
            _Pragma("unroll") for (int j = 0; j < 4; ++j) {                   \
                acc[i][j] = __builtin_amdgcn_mfma_f32_16x16x32_f16(fah[i], fbh[j], acc[i][j], 0, 0, 0); \
                acc[i][j] = __builtin_amdgcn_mfma_f32_16x16x32_f16(fah[i], fbl[j], acc[i][j], 0, 0, 0); \
                acc[i][j] = __builtin_amdgcn_mfma_f32_16x16x32_f16(fal[i], fbh[j], acc[i][j], 0, 0, 0); \
            }                                                                 \
    }

// ---------------------------------------------------------------------------
// Merged projections (512 blocks, 2 blocks/CU).
// z=0: q-proj + gate; z=1,y<32: k-proj split; z=1,y>=32: v-proj fp32.
// ---------------------------------------------------------------------------
__global__ __launch_bounds__(256, 2) void k_proj_all(
    const _Float16* __restrict__ hsTh, const _Float16* __restrict__ hsTl,
    const _Float16* __restrict__ cbhi, const _Float16* __restrict__ cblo,
    const _Float16* __restrict__ wqTh, const _Float16* __restrict__ wqTl,
    const _Float16* __restrict__ wkTh, const _Float16* __restrict__ wkTl,
    const _Float16* __restrict__ wvTh, const _Float16* __restrict__ wvTl,
    const float* __restrict__ bq, const float* __restrict__ bk, const float* __restrict__ bv,
    const float* __restrict__ Wp, const float* __restrict__ bp,
    _Float16* __restrict__ qhi, _Float16* __restrict__ qlo,
    _Float16* __restrict__ khi, _Float16* __restrict__ klo, float* __restrict__ vproj)
{
    const int z    = blockIdx.z;
    const int y    = blockIdx.y;
    const int c0   = blockIdx.x * 128;
    const int path = z == 0 ? 0 : (y < 32 ? 1 : 2);
    const int m0   = (z == 0 ? y : (y & 31)) * 128;
    const int hblk = c0 >> 7;

    const _Float16* srcAh = z == 0 ? hsTh : cbhi;
    const _Float16* srcAl = z == 0 ? hsTl : cblo;
    const _Float16* bTh   = path == 0 ? wqTh : path == 1 ? wkTh : wvTh;
    const _Float16* bTl   = path == 0 ? wqTl : path == 1 ? wkTl : wvTl;
    const float*    bias  = path == 0 ? bq   : path == 1 ? bk   : bv;

    MFMA_TILE_DECLS
    __shared__ float wp_sh[32];
    __shared__ float gate_sh[128];
    float gate = 0.f;

    const _Float16* pAh = srcAh + (size_t)(m0 + w * 32 + rA) * CC + cA;
    const _Float16* pAl = srcAl + (size_t)(m0 + w * 32 + rA) * CC + cA;
    const _Float16* pBh = bTh   + (size_t)(c0 + w * 32 + rA) * CC + cA;
    const _Float16* pBl = bTl   + (size_t)(c0 + w * 32 + rA) * CC + cA;

    for (int k0 = 0; k0 < CC; k0 += 32) {
        MFMA_TILE_STAGE(pAh, pAl, pBh, pBl, k0, CC)
        if (path == 0 && tid < 32) wp_sh[tid] = Wp[(size_t)(k0 + tid) * HH + hblk];
        __syncthreads();
        MFMA_TILE_COMPUTE
        if (path == 0 && tid < 128) {
            #pragma unroll
            for (int s = 0; s < 4; ++s) {
                f16x8 hv = *(const f16x8*)&Ah[tid][s * 8];
                f16x8 lv = *(const f16x8*)&Al[tid][s * 8];
                #pragma unroll
                for (int jj = 0; jj < 8; ++jj)
                    gate = fmaf((float)hv[jj] + (float)lv[jj], wp_sh[s * 8 + jj], gate);
            }
        }
        __syncthreads();
    }

    if (path == 0) {
        if (tid < 128)
            gate_sh[tid] = (gate * (1.0f / 512.0f) + bp[hblk]) * KFAC;
        __syncthreads();
        #pragma unroll
        for (int i = 0; i < 4; ++i)
            #pragma unroll
            for (int j = 0; j < 4; ++j) {
                int col = c0 + wn + j * 16 + l15;
                float bi = bias[col];
                #pragma unroll
                for (int r = 0; r < 4; ++r) {
                    int rloc = wm + i * 16 + quad * 4 + r;
                    float v = fmaf(acc[i][j][r], INV_S18, bi) * gate_sh[rloc];
                    HL s = split512(v);
                    qhi[(size_t)(m0 + rloc) * CC + col] = s.h;
                    qlo[(size_t)(m0 + rloc) * CC + col] = s.l;
                }
            }
    } else if (path == 1) {
        #pragma unroll
        for (int i = 0; i < 4; ++i)
            #pragma unroll
            for (int j = 0; j < 4; ++j) {
                int col = c0 + wn + j * 16 + l15;
                float bi = bias[col];
                #pragma unroll
                for (int r = 0; r < 4; ++r) {
                    int row = m0 + wm + i * 16 + quad * 4 + r;
                    float v = fmaf(acc[i][j][r], INV_S18, bi);
                    HL s = split512(v);
                    khi[(size_t)row * CC + col] = s.h;
                    klo[(size_t)row * CC + col] = s.l;
                }
            }
    } else {
        #pragma unroll
        for (int i = 0; i < 4; ++i)
            #pragma unroll
            for (int j = 0; j < 4; ++j) {
                int col = c0 + wn + j * 16 + l15;
                float bi = bias[col];
                #pragma unroll
                for (int r = 0; r < 4; ++r) {
                    int row = m0 + wm + i * 16 + quad * 4 + r;
                    vproj[(size_t)row * CC + col] = fmaf(acc[i][j][r], INV_S18, bi);
                }
            }
    }
}

// ---------------------------------------------------------------------------
// Logits: 256x256-tile phase-split GEMM over virtual K'=1536 (3-term split:
// (khi,qhi)+(klo,qhi)+(khi,qlo)). 8 waves (2Mx4N), BK=64, double-buffered
// 128KB LDS. T2: full 3-bit XOR swizzle (chunk ^= row&7 at 16B granularity),
// applied as linear LDS dest + pre-swizzled global source (gld_lds rule) +
// swizzled ds_read. T4: staging re-chunked by CONSUMPTION order
// (A0'={rows 0-63,128-191}, B0'={0-31,64-95,128-159,192-223}, etc.), issued
// A0',B0',B1',A1' across the 4 phases -> steady-state vmcnt(4), never 0.
// T5: setprio around each 16-MFMA cluster. Fused partial argmax.
// ---------------------------------------------------------------------------
#define BAR   __builtin_amdgcn_s_barrier()
#define LGKM0 { asm volatile("s_waitcnt lgkmcnt(0)" ::: "memory"); __builtin_amdgcn_sched_barrier(0); }
#define PRIO1 __builtin_amdgcn_s_setprio(1)
#define PRIO0 __builtin_amdgcn_s_setprio(0)
#define VMW(N) asm volatile("s_waitcnt vmcnt(" #N ")" ::: "memory")

// Stage A sub-block HF (rows HF*64..HF*64+63 of both 128-row halves).
// 2 gld16/wave; uniform issue order across waves.
#define ST_A(D, HF, SRC) {                                                    \
    _Pragma("unroll") for (int qi_ = 0; qi_ < 2; ++qi_) {                     \
        int q_  = w * 2 + qi_;                                                \
        int hf_ = q_ >> 3;                                                    \
        int R0_ = (q_ & 7) * 8;                                               \
        gld16((SRC) + (size_t)(hf_ * 128 + (HF) * 64 + R0_) * CC + lsrc,      \
              &smem[(D) * 32768 + hf_ * 8192 + ((HF) * 64 + R0_) * 64]);      \
    }                                                                         \
}
// Stage B sub-strips HF (rows s*64+HF*32..+31 for s=0..3).
#define ST_B(D, HF, SRC) {                                                    \
    _Pragma("unroll") for (int qi_ = 0; qi_ < 2; ++qi_) {                     \
        int q_  = w * 2 + qi_;                                                \
        int s_  = q_ >> 2;                                                    \
        int R0_ = (q_ & 3) * 8;                                               \
        int tr_ = s_ * 64 + (HF) * 32 + R0_;                                  \
        gld16((SRC) + (size_t)tr_ * CC + lsrc,                                \
              &smem[(D) * 32768 + 16384 + (tr_ >> 7) * 8192 + (tr_ & 127) * 64]); \
    }                                                                         \
}
#define RD_A(D, HF) {                                                         \
    _Pragma("unroll") for (int ii = 0; ii < 4; ++ii) {                        \
        ah[ii][0] = *(const f16x8*)&smem[(D) * 32768 + ha * 8192 +            \
                        ((HF) * 4 + ii) * 1024 + rdk0];                       \
        ah[ii][1] = *(const f16x8*)&smem[(D) * 32768 + ha * 8192 +            \
                        ((HF) * 4 + ii) * 1024 + rdk1];                       \
    }                                                                         \
}
#define RD_B(D, HF) {                                                         \
    _Pragma("unroll") for (int jj = 0; jj < 2; ++jj) {                        \
        bf[(HF) * 2 + jj][0] = *(const f16x8*)&smem[(D) * 32768 + 16384 +     \
            hb * 8192 + wb64f + ((HF) * 2 + jj) * 1024 + rdk0];               \
        bf[(HF) * 2 + jj][1] = *(const f16x8*)&smem[(D) * 32768 + 16384 +     \
            hb * 8192 + wb64f + ((HF) * 2 + jj) * 1024 + rdk1];               \
    }                                                                         \
}
#define MM(AH, BH) {                                                          \
    _Pragma("unroll") for (int kk = 0; kk < 2; ++kk)                          \
      _Pragma("unroll") for (int ii = 0; ii < 4; ++ii)                        \
        _Pragma("unroll") for (int jj = 0; jj < 2; ++jj)                      \
          acc[(AH) * 4 + ii][(BH) * 2 + jj] =                                 \
            __builtin_amdgcn_mfma_f32_16x16x32_f16(ah[ii][kk],                \
                bf[(BH) * 2 + jj][kk], acc[(AH) * 4 + ii][(BH) * 2 + jj], 0, 0, 0); \
}
// Main K-tile: consume buf D, stage tile (into 1-D) via AN/BN pointers.
// vmcnt(4): 2 loads/chunk/wave, 8 in flight max, oldest 4 retired at waits.
#define KTILE(D, AN, BN) {                                                    \
    ST_A(1 - (D), 0, AN);                                                     \
    RD_A(D, 0); RD_B(D, 0);                                                   \
    BAR; LGKM0; PRIO1; MM(0, 0); PRIO0; VMW(4); BAR;                          \
    ST_B(1 - (D), 0, BN);                                                     \
    RD_B(D, 1);                                                               \
    BAR; LGKM0; PRIO1; MM(0, 1); PRIO0; VMW(4); BAR;                          \
    ST_B(1 - (D), 1, BN);                                                     \
    RD_A(D, 1);                                                               \
    BAR; LGKM0; PRIO1; MM(1, 1); PRIO0; BAR;                                  \
    ST_A(1 - (D), 1, AN);                                                     \
    PRIO1; MM(1, 0); PRIO0; VMW(4); BAR;                                      \
}
#define KTILE_LAST(D) {                                                       \
    RD_A(D, 0); RD_B(D, 0);                                                   \
    BAR; LGKM0; PRIO1; MM(0, 0); PRIO0; VMW(2); BAR;                          \
    RD_B(D, 1);                                                               \
    BAR; LGKM0; PRIO1; MM(0, 1); PRIO0; VMW(0); BAR;                          \
    RD_A(D, 1);                                                               \
    BAR; LGKM0; PRIO1; MM(1, 1); PRIO0; BAR;                                  \
    PRIO1; MM(1, 0); PRIO0;                                                   \
}

__global__ __launch_bounds__(512, 2) void k_logits_8p(
    const _Float16* __restrict__ khi, const _Float16* __restrict__ klo,
    const _Float16* __restrict__ qhi, const _Float16* __restrict__ qlo,
    float* __restrict__ logits,       // [B][N][T]
    float* __restrict__ pval,         // [B][16][T]
    int*   __restrict__ pidx)         // [B][16][T]
{
    __shared__ __align__(16) _Float16 smem[65536];   // 128 KB: 2 x (A 32KB + B 32KB)

    // Bijective XCD-aware swizzle of the flat block id (512 = 8 XCD x 64).
    const int f  = blockIdx.x + 8 * (blockIdx.y + 16 * blockIdx.z);
    const int fs = (f & 7) * 64 + (f >> 3);
    const int t0 = (fs & 7) * 256;
    const int by = (fs >> 3) & 15;
    const int b  = fs >> 7;
    const int n0 = by * 256;

    const int tid  = threadIdx.x;
    const int w    = tid >> 6;
    const int l    = tid & 63;
    const int quad = l >> 4;
    const int l15  = l & 15;
    const int wm   = (w >> 2) * 128;   // m (n-rows) offset; A-half = w>>2
    const int ha   = w >> 2;
    const int wn   = (w & 3) * 64;     // n (t-cols) offset
    const int hb   = (w & 3) >> 1;     // B-half
    const int wb64f = (w & 1) * 4096;  // row offset within B-half (f16)

    const size_t arow0 = (size_t)n0 * CC;
    const size_t brow0 = ((size_t)b * TT + t0) * CC;

    // Per-lane staging source offset (f16): row = l>>3 within the 8-row
    // block, source chunk = (l&7) ^ (row&7)  (inverse of the read swizzle;
    // LDS dest stays linear for global_load_lds).
    const int    lrow = l >> 3;
    const int    lchk = (l & 7) ^ lrow;
    const size_t lsrc = (size_t)lrow * CC + (size_t)lchk * 8;

    // Swizzled ds_read offsets (f16) within a row: chunk = (quad+4k)^(row&7).
    const int cs0  = quad ^ (l15 & 7);
    const int rdk0 = l15 * 64 + cs0 * 8;
    const int rdk1 = l15 * 64 + (cs0 ^ 4) * 8;

    f32x4 acc[8][4];
    #pragma unroll
    for (int i = 0; i < 8; ++i)
        #pragma unroll
        for (int j = 0; j < 4; ++j)
            acc[i][j] = (f32x4){0.f, 0.f, 0.f, 0.f};
    f16x8 ah[4][2];
    f16x8 bf[4][2];

    // Prologue: stage tile 0 (chunk order A0',B0',B1',A1'), wait A0'+B0'.
    {
        const _Float16* a0_ = khi + arow0;
        const _Float16* b0_ = qhi + brow0;
        ST_A(0, 0, a0_); ST_B(0, 0, b0_); ST_B(0, 1, b0_); ST_A(0, 1, a0_);
    }
    VMW(4); BAR;

    // 24 virtual K-tiles (3 segments x 8). Tile kt lives in buf kt&1.
    #pragma unroll 1
    for (int kt2 = 0; kt2 < 11; ++kt2) {
        {
            int ktn = kt2 * 2 + 1;
            const _Float16* an = (ktn >= 8 && ktn < 16 ? klo : khi) + arow0 + (ktn & 7) * 64;
            const _Float16* bn = (ktn >= 16 ? qlo : qhi) + brow0 + (ktn & 7) * 64;
            KTILE(0, an, bn);
        }
        {
            int ktn = kt2 * 2 + 2;
            const _Float16* an = (ktn >= 8 && ktn < 16 ? klo : khi) + arow0 + (ktn & 7) * 64;
            const _Float16* bn = (ktn >= 16 ? qlo : qhi) + brow0 + (ktn & 7) * 64;
            KTILE(1, an, bn);
        }
    }
    {   // consume tile 22, stage tile 23
        const _Float16* an = khi + arow0 + 7 * 64;   // ktn=23 -> seg 2 A=khi
        const _Float16* bn = qlo + brow0 + 7 * 64;   //          B=qlo
        KTILE(0, an, bn);
    }
    KTILE_LAST(1);

    // Epilogue: store logits (i-outer, j-inner).
    {
        const size_t lb = ((size_t)b * NN + n0 + wm) * TT + t0 + wn;
        #pragma unroll
        for (int i = 0; i < 8; ++i)
            #pragma unroll
            for (int r = 0; r < 4; ++r) {
                const size_t rowoff = lb + (size_t)(i * 16 + quad * 4 + r) * TT;
                #pragma unroll
                for (int j = 0; j < 4; ++j)
                    logits[rowoff + j * 16 + l15] = acc[i][j][r] * INV_SCALE2;
            }
    }
    // Partial argmax over this block's 256 n-rows (first-max tie-break).
    float bvj[4]; int bnj[4];
    #pragma unroll
    for (int j = 0; j < 4; ++j) {
        float bv = -3.0e38f; int bn = 0;
        #pragma unroll
        for (int i = 0; i < 8; ++i)
            #pragma unroll
            for (int r = 0; r < 4; ++r) {
                float v = acc[i][j][r] * INV_SCALE2;
                int row = n0 + wm + i * 16 + quad * 4 + r;
                if (v > bv) { bv = v; bn = row; }
            }
        #pragma unroll
        for (int m = 16; m <= 32; m <<= 1) {
            float ov = __shfl_xor(bv, m, 64);
            int   on = __shfl_xor(bn, m, 64);
            if (ov > bv || (ov == bv && on < bn)) { bv = ov; bn = on; }
        }
        bvj[j] = bv; bnj[j] = bn;
    }
    // Merge wave pairs (w, w+4): lower rows (w<4) win ties via strict >.
    float* rv = (float*)smem;
    int*   ri = (int*)(smem + 1024);
    __syncthreads();
    if (w >= 4 && l < 16) {
        #pragma unroll
        for (int j = 0; j < 4; ++j) {
            rv[wn + j * 16 + l] = bvj[j];
            ri[wn + j * 16 + l] = bnj[j];
        }
    }
    __syncthreads();
    if (w < 4 && l < 16) {
        #pragma unroll
        for (int j = 0; j < 4; ++j) {
            int cl = wn + j * 16 + l;
            float bv = bvj[j]; int bn = bnj[j];
            float ov = rv[cl];
            if (ov > bv) { bv = ov; bn = ri[cl]; }
            size_t o = ((size_t)b * 16 + by) * TT + t0 + cl;
            pval[o] = bv;
            pidx[o] = bn;
        }
    }
}

// ---------------------------------------------------------------------------
// Finalize: reduce 16 partial argmaxes per (b,t), gather z_q rows from vproj.
// ---------------------------------------------------------------------------
__global__ __launch_bounds__(256) void k_finalize(
    const float* __restrict__ pval,    // [B][16][T]
    const int*   __restrict__ pidx,    // [B][16][T]
    const float* __restrict__ vproj,   // [N][C]
    float* __restrict__ idx_out,       // [B][T] (float)
    float* __restrict__ zq)            // [B][C][T]
{
    const int b  = blockIdx.y;
    const int t0 = blockIdx.x * 32;
    const int tid = threadIdx.x;

    __shared__ int sfin[32];
    if (tid < 32) {
        const int t = t0 + tid;
        float bv = -3.0e38f; int bn = 0;
        #pragma unroll
        for (int k = 0; k < 16; ++k) {
            size_t o = ((size_t)b * 16 + k) * TT + t;
            float v = pval[o];
            if (v > bv) { bv = v; bn = pidx[o]; }
        }
        idx_out[(size_t)b * TT + t] = (float)bn;
        sfin[tid] = bn;
    }
    __syncthreads();
    for (int pos = tid; pos < 32 * CC; pos += 256) {
        int c = pos >> 5, tl = pos & 31;
        zq[((size_t)b * CC + c) * TT + t0 + tl] = vproj[(size_t)sfin[tl] * CC + c];
    }
}

// ---------------------------------------------------------------------------
extern "C" void kernel_launch(void* const* d_in, const int* in_sizes, int n_in,
                              void* d_out, int out_size, void* d_ws, size_t ws_size,
                              hipStream_t stream)
{
    (void)in_sizes; (void)n_in; (void)out_size; (void)ws_size;
    const float* hs = (const float*)d_in[0];
    const float* cb = (const float*)d_in[1];
    const float* Wq = (const float*)d_in[2];
    const float* bq = (const float*)d_in[3];
    const float* Wk = (const float*)d_in[4];
    const float* bk = (const float*)d_in[5];
    const float* Wv = (const float*)d_in[6];
    const float* bv = (const float*)d_in[7];
    const float* Wp = (const float*)d_in[8];
    const float* bp = (const float*)d_in[9];

    char* ws = (char*)d_ws;
    const size_t MB = 1024 * 1024;
    _Float16* hsTh = (_Float16*)(ws);              // [B*T][C] 8 MB
    _Float16* hsTl = (_Float16*)(ws + 8  * MB);
    _Float16* qhi  = (_Float16*)(ws + 16 * MB);    // [B*T][C] 8 MB
    _Float16* qlo  = (_Float16*)(ws + 24 * MB);
    _Float16* cbhi = (_Float16*)(ws + 32 * MB);    // [N][C]   4 MB
    _Float16* cblo = (_Float16*)(ws + 36 * MB);
    _Float16* khi  = (_Float16*)(ws + 40 * MB);    // [N][C]   4 MB
    _Float16* klo  = (_Float16*)(ws + 44 * MB);
    float*    vproj= (float*)   (ws + 48 * MB);    // [N][C]   8 MB fp32
    _Float16* wqTh = (_Float16*)(ws + 56 * MB);    // [C][C]   0.5 MB each
    _Float16* wqTl = (_Float16*)(ws + 56 * MB + 524288);
    _Float16* wkTh = (_Float16*)(ws + 57 * MB);
    _Float16* wkTl = (_Float16*)(ws + 57 * MB + 524288);
    _Float16* wvTh = (_Float16*)(ws + 58 * MB);
    _Float16* wvTl = (_Float16*)(ws + 58 * MB + 524288);
    // Partial argmax buffers alias the (dead-after-proj) cbhi region.
    float* pval = (float*)(ws + 32 * MB);          // [B][16][T] 512 KB
    int*   pidx = (int*)  (ws + 33 * MB);

    float* logits = (float*)d_out;                  // B*N*T
    float* idxf   = logits + (size_t)BB * NN * TT;  // B*T
    float* zq     = idxf + (size_t)BB * TT;         // B*C*T

    // Prep
    k_split<<<dim3((NN * CC / 4 + 255) / 256), 256, 0, stream>>>(
        cb, cbhi, cblo, NN * CC / 4);
    k_tsplit<<<dim3(TT / 64, CC / 64, BB), 256, 0, stream>>>(
        hs, hsTh, hsTl, (long)CC * TT, (long)TT * CC, TT, CC);
    k_tsplit_w<<<dim3(CC / 64, CC / 64, 3), 256, 0, stream>>>(
        Wq, Wk, Wv, wqTh, wkTh, wvTh, wqTl, wkTl, wvTl);

    // All projections in one dispatch (512 blocks -> 2 blocks/CU)
    k_proj_all<<<dim3(CC / 128, 64, 2), 256, 0, stream>>>(
        hsTh, hsTl, cbhi, cblo,
        wqTh, wqTl, wkTh, wkTl, wvTh, wvTl,
        bq, bk, bv, Wp, bp,
        qhi, qlo, khi, klo, vproj);

    // Logits: 256^2-tile phase-split GEMM + fused partial argmax
    k_logits_8p<<<dim3(TT / 256, NN / 256, BB), 512, 0, stream>>>(
        khi, klo, qhi, qlo, logits, pval, pidx);

    // Final argmax reduce + gather
    k_finalize<<<dim3(TT / 32, BB), 256, 0, stream>>>(
        pval, pidx, vproj, idxf, zq);
}

// Round 4
// 335.817 us; speedup vs baseline: 1.0023x; 1.0023x over previous
//
#include <hip/hip_runtime.h>
#include <hip/hip_bf16.h>
#include <cstddef>
#include <cstdint>

// Problem constants
#define BB 4
#define CC 512
#define TT 2048
#define NN 4096
#define HH 4
// d = CC/HH = 128

constexpr float KFAC       = 0.04419417382415922f;           // 1/(sqrt(128)*2)
constexpr float INV_S18    = 1.0f / 262144.0f;               // 2^-18 (undo two x512)
constexpr float INV_SCALE2 = 1.0f / (512.0f * 512.0f);

typedef _Float16 f16x8 __attribute__((ext_vector_type(8)));
typedef _Float16 f16x4 __attribute__((ext_vector_type(4)));
typedef float    f32x4 __attribute__((ext_vector_type(4)));

__device__ __forceinline__ void gld16(const void* g, void* s) {
    __builtin_amdgcn_global_load_lds(
        (const __attribute__((address_space(1))) void*)g,
        (__attribute__((address_space(3))) void*)s, 16, 0, 0);
}

struct HL { _Float16 h, l; };
__device__ __forceinline__ HL split512(float x) {
    float v = x * 512.0f;
    _Float16 h = (_Float16)v;
    return { h, (_Float16)(v - (float)h) };
}

// ---------------------------------------------------------------------------
// Prep 1: elementwise split (x512) of cb [N][C] -> cbhi/cblo fp16 [N][C]
// ---------------------------------------------------------------------------
__global__ __launch_bounds__(256) void k_split(
    const float* __restrict__ src, _Float16* __restrict__ hi, _Float16* __restrict__ lo, int n4)
{
    int q = blockIdx.x * 256 + threadIdx.x;
    if (q >= n4) return;
    float4 v = *(const float4*)(src + (size_t)q * 4);
    f16x4 H, L;
    HL a = split512(v.x); H[0] = a.h; L[0] = a.l;
    HL b = split512(v.y); H[1] = b.h; L[1] = b.l;
    HL c = split512(v.z); H[2] = c.h; L[2] = c.l;
    HL d = split512(v.w); H[3] = d.h; L[3] = d.l;
    *(f16x4*)(hi + (size_t)q * 4) = H;
    *(f16x4*)(lo + (size_t)q * 4) = L;
}

// ---------------------------------------------------------------------------
// Prep 2: transpose + split (x512): src fp32 [R][S] -> dst hi/lo fp16 [S][R]
// ---------------------------------------------------------------------------
__device__ __forceinline__ void tsplit_body(
    const float* __restrict__ src, _Float16* __restrict__ hi, _Float16* __restrict__ lo,
    int S, int R, int r0, int s0)
{
    __shared__ float ls[64][65];
    const int tid = threadIdx.x;
    #pragma unroll
    for (int i = 0; i < 4; ++i) {
        int q = tid + i * 256;
        int row = q >> 4, c4 = (q & 15) * 4;
        float4 v = *(const float4*)(src + (size_t)(r0 + row) * S + s0 + c4);
        ls[row][c4] = v.x; ls[row][c4 + 1] = v.y;
        ls[row][c4 + 2] = v.z; ls[row][c4 + 3] = v.w;
    }
    __syncthreads();
    #pragma unroll
    for (int i = 0; i < 2; ++i) {
        int q = tid + i * 256;
        int orow = q >> 3, seg = (q & 7) * 8;
        f16x8 H, L;
        #pragma unroll
        for (int j = 0; j < 8; ++j) {
            HL s = split512(ls[seg + j][orow]);
            H[j] = s.h; L[j] = s.l;
        }
        size_t off = (size_t)(s0 + orow) * R + r0 + seg;
        *(f16x8*)(hi + off) = H;
        *(f16x8*)(lo + off) = L;
    }
}

__global__ __launch_bounds__(256) void k_tsplit(
    const float* __restrict__ src, _Float16* __restrict__ hi, _Float16* __restrict__ lo,
    long sbatch, long dbatch, int S, int R)
{
    src += (size_t)blockIdx.z * sbatch;
    hi  += (size_t)blockIdx.z * dbatch;
    lo  += (size_t)blockIdx.z * dbatch;
    tsplit_body(src, hi, lo, S, R, blockIdx.y * 64, blockIdx.x * 64);
}

__global__ __launch_bounds__(256) void k_tsplit_w(
    const float* __restrict__ w0, const float* __restrict__ w1, const float* __restrict__ w2,
    _Float16* __restrict__ h0, _Float16* __restrict__ h1, _Float16* __restrict__ h2,
    _Float16* __restrict__ l0, _Float16* __restrict__ l1, _Float16* __restrict__ l2)
{
    const int z = blockIdx.z;
    const float* src = z == 0 ? w0 : z == 1 ? w1 : w2;
    _Float16* hi = z == 0 ? h0 : z == 1 ? h1 : h2;
    _Float16* lo = z == 0 ? l0 : z == 1 ? l1 : l2;
    tsplit_body(src, hi, lo, CC, CC, blockIdx.y * 64, blockIdx.x * 64);
}

// ---------------------------------------------------------------------------
// MFMA tile core (projections): 128x128 tile, BK=32, 4 waves, 3-term split.
// ---------------------------------------------------------------------------
#define MFMA_TILE_DECLS                                                       \
    __shared__ __align__(16) _Float16 Ah[128][32];                            \
    __shared__ __align__(16) _Float16 Al[128][32];                            \
    __shared__ __align__(16) _Float16 Bh[128][32];                            \
    __shared__ __align__(16) _Float16 Bl[128][32];                            \
    const int tid  = threadIdx.x;                                             \
    const int w    = tid >> 6;                                                \
    const int l    = tid & 63;                                                \
    const int quad = l >> 4;                                                  \
    const int l15  = l & 15;                                                  \
    const int wm   = (w >> 1) * 64;                                           \
    const int wn   = (w & 1) * 64;                                            \
    const int rA   = l >> 2;                                                  \
    const int cA   = (l & 3) * 8;                                             \
    f32x4 acc[4][4];                                                          \
    _Pragma("unroll") for (int i = 0; i < 4; ++i)                             \
        _Pragma("unroll") for (int j = 0; j < 4; ++j)                         \
            acc[i][j] = (f32x4){0.f, 0.f, 0.f, 0.f};

#define MFMA_TILE_STAGE(pAh, pAl, pBh, pBl, k0, srcStride)                    \
    gld16(pAh + k0,                    &Ah[w * 32][0]);                       \
    gld16(pAh + k0 + 16 * (srcStride), &Ah[w * 32 + 16][0]);                  \
    gld16(pAl + k0,                    &Al[w * 32][0]);                       \
    gld16(pAl + k0 + 16 * (srcStride), &Al[w * 32 + 16][0]);                  \
    gld16(pBh + k0,                    &Bh[w * 32][0]);                       \
    gld16(pBh + k0 + 16 * (srcStride), &Bh[w * 32 + 16][0]);                  \
    gld16(pBl + k0,                    &Bl[w * 32][0]);                       \
    gld16(pBl + k0 + 16 * (srcStride), &Bl[w * 32 + 16][0]);

#define MFMA_TILE_COMPUTE                                                     \
    {                                                                         \
        f16x8 fah[4], fal[4], fbh[4], fbl[4];                                 \
        _Pragma("unroll") for (int i = 0; i < 4; ++i) {                       \
            fah[i] = *(const f16x8*)&Ah[wm + i * 16 + l15][quad * 8];         \
            fal[i] = *(const f16x8*)&Al[wm + i * 16 + l15][quad * 8];         \
            fbh[i] = *(const f16x8*)&Bh[wn + i * 16 + l15][quad * 8];         \
            fbl[i] = *(const f16x8*)&Bl[wn + i * 16 + l15][quad * 8];         \
        }                                                                     \
        _Pragma("unroll") for (int i = 0; i < 4; ++i)                         \
            _Pragma("unroll") for (int j = 0; j < 4; ++j) {                   \
                acc[i][j] = __builtin_amdgcn_mfma_f32_16x16x32_f16(fah[i], fbh[j], acc[i][j], 0, 0, 0); \
                acc[i][j] = __builtin_amdgcn_mfma_f32_16x16x32_f16(fah[i], fbl[j], acc[i][j], 0, 0, 0); \
                acc[i][j] = __builtin_amdgcn_mfma_f32_16x16x32_f16(fal[i], fbh[j], acc[i][j], 0, 0, 0); \
            }                                                                 \
    }

// ---------------------------------------------------------------------------
// Merged projections (512 blocks, 2 blocks/CU).
// z=0: q-proj + gate; z=1,y<32: k-proj split; z=1,y>=32: v-proj fp32.
// ---------------------------------------------------------------------------
__global__ __launch_bounds__(256, 2) void k_proj_all(
    const _Float16* __restrict__ hsTh, const _Float16* __restrict__ hsTl,
    const _Float16* __restrict__ cbhi, const _Float16* __restrict__ cblo,
    const _Float16* __restrict__ wqTh, const _Float16* __restrict__ wqTl,
    const _Float16* __restrict__ wkTh, const _Float16* __restrict__ wkTl,
    const _Float16* __restrict__ wvTh, const _Float16* __restrict__ wvTl,
    const float* __restrict__ bq, const float* __restrict__ bk, const float* __restrict__ bv,
    const float* __restrict__ Wp, const float* __restrict__ bp,
    _Float16* __restrict__ qhi, _Float16* __restrict__ qlo,
    _Float16* __restrict__ khi, _Float16* __restrict__ klo, float* __restrict__ vproj)
{
    const int z    = blockIdx.z;
    const int y    = blockIdx.y;
    const int c0   = blockIdx.x * 128;
    const int path = z == 0 ? 0 : (y < 32 ? 1 : 2);
    const int m0   = (z == 0 ? y : (y & 31)) * 128;
    const int hblk = c0 >> 7;

    const _Float16* srcAh = z == 0 ? hsTh : cbhi;
    const _Float16* srcAl = z == 0 ? hsTl : cblo;
    const _Float16* bTh   = path == 0 ? wqTh : path == 1 ? wkTh : wvTh;
    const _Float16* bTl   = path == 0 ? wqTl : path == 1 ? wkTl : wvTl;
    const float*    bias  = path == 0 ? bq   : path == 1 ? bk   : bv;

    MFMA_TILE_DECLS
    __shared__ float wp_sh[32];
    __shared__ float gate_sh[128];
    float gate = 0.f;

    const _Float16* pAh = srcAh + (size_t)(m0 + w * 32 + rA) * CC + cA;
    const _Float16* pAl = srcAl + (size_t)(m0 + w * 32 + rA) * CC + cA;
    const _Float16* pBh = bTh   + (size_t)(c0 + w * 32 + rA) * CC + cA;
    const _Float16* pBl = bTl   + (size_t)(c0 + w * 32 + rA) * CC + cA;

    for (int k0 = 0; k0 < CC; k0 += 32) {
        MFMA_TILE_STAGE(pAh, pAl, pBh, pBl, k0, CC)
        if (path == 0 && tid < 32) wp_sh[tid] = Wp[(size_t)(k0 + tid) * HH + hblk];
        __syncthreads();
        MFMA_TILE_COMPUTE
        if (path == 0 && tid < 128) {
            #pragma unroll
            for (int s = 0; s < 4; ++s) {
                f16x8 hv = *(const f16x8*)&Ah[tid][s * 8];
                f16x8 lv = *(const f16x8*)&Al[tid][s * 8];
                #pragma unroll
                for (int jj = 0; jj < 8; ++jj)
                    gate = fmaf((float)hv[jj] + (float)lv[jj], wp_sh[s * 8 + jj], gate);
            }
        }
        __syncthreads();
    }

    if (path == 0) {
        if (tid < 128)
            gate_sh[tid] = (gate * (1.0f / 512.0f) + bp[hblk]) * KFAC;
        __syncthreads();
        #pragma unroll
        for (int i = 0; i < 4; ++i)
            #pragma unroll
            for (int j = 0; j < 4; ++j) {
                int col = c0 + wn + j * 16 + l15;
                float bi = bias[col];
                #pragma unroll
                for (int r = 0; r < 4; ++r) {
                    int rloc = wm + i * 16 + quad * 4 + r;
                    float v = fmaf(acc[i][j][r], INV_S18, bi) * gate_sh[rloc];
                    HL s = split512(v);
                    qhi[(size_t)(m0 + rloc) * CC + col] = s.h;
                    qlo[(size_t)(m0 + rloc) * CC + col] = s.l;
                }
            }
    } else if (path == 1) {
        #pragma unroll
        for (int i = 0; i < 4; ++i)
            #pragma unroll
            for (int j = 0; j < 4; ++j) {
                int col = c0 + wn + j * 16 + l15;
                float bi = bias[col];
                #pragma unroll
                for (int r = 0; r < 4; ++r) {
                    int row = m0 + wm + i * 16 + quad * 4 + r;
                    float v = fmaf(acc[i][j][r], INV_S18, bi);
                    HL s = split512(v);
                    khi[(size_t)row * CC + col] = s.h;
                    klo[(size_t)row * CC + col] = s.l;
                }
            }
    } else {
        #pragma unroll
        for (int i = 0; i < 4; ++i)
            #pragma unroll
            for (int j = 0; j < 4; ++j) {
                int col = c0 + wn + j * 16 + l15;
                float bi = bias[col];
                #pragma unroll
                for (int r = 0; r < 4; ++r) {
                    int row = m0 + wm + i * 16 + quad * 4 + r;
                    vproj[(size_t)row * CC + col] = fmaf(acc[i][j][r], INV_S18, bi);
                }
            }
    }
}

// ---------------------------------------------------------------------------
// Logits: 256x256-tile GEMM over virtual K'=1536 (3-term split), rebuilt as
// BK=32 with a 4-buffer LDS ring (4 x 32KB = 128KB): tile t+3 staged during
// tile t -> ~6-phase load deadline (covers loaded L3/HBM latency). Per tile:
// 2 phases x 16 MFMA; counted vmcnt(8) once per tile (12 loads in flight).
// LDS layout: paired 128B rows (global rows r, r+128 share a row; 8 x 16B
// chunks) with 3-bit XOR swizzle chunk^=(row&7) -> reads at free 2-way.
// Staging: linear LDS dest + inverse-swizzled global source (rule 21).
// Fused partial argmax over the 256 n-rows -> pval/pidx [B][16][T].
// ---------------------------------------------------------------------------
#define BAR   __builtin_amdgcn_s_barrier()
#define LGKM0 { asm volatile("s_waitcnt lgkmcnt(0)" ::: "memory"); __builtin_amdgcn_sched_barrier(0); }
#define PRIO1 __builtin_amdgcn_s_setprio(1)
#define PRIO0 __builtin_amdgcn_s_setprio(0)
#define VMW(N) asm volatile("s_waitcnt vmcnt(" #N ")" ::: "memory")

// Stage A (2 gld16/wave) / B of one BK=32 tile into ring buffer BUF.
#define ST_A3(BUF, SRC) {                                                     \
    gld16((SRC) + lsrc,           &smem[(BUF) * 16384 + w * 512]);            \
    gld16((SRC) + lsrc + 64 * CC, &smem[(BUF) * 16384 + 4096 + w * 512]);     \
}
#define ST_B3(BUF, SRC) {                                                     \
    gld16((SRC) + lsrc,           &smem[(BUF) * 16384 + 8192 + w * 512]);     \
    gld16((SRC) + lsrc + 64 * CC, &smem[(BUF) * 16384 + 12288 + w * 512]);    \
}
// Read 4 A row-frags (half H: frags H*4..H*4+3) / all 4 B col-frags.
#define RD_A3(BUF, H) {                                                       \
    _Pragma("unroll") for (int ii = 0; ii < 4; ++ii)                          \
        ah[ii] = *(const f16x8*)&smem[(BUF) * 16384 + ((H) * 4 + ii) * 1024 + baseRdA]; \
}
#define RD_B3(BUF) {                                                          \
    _Pragma("unroll") for (int jj = 0; jj < 4; ++jj)                          \
        bf[jj] = *(const f16x8*)&smem[(BUF) * 16384 + baseRdB + jj * 1024];   \
}
#define MM3(IOFF) {                                                           \
    _Pragma("unroll") for (int ii = 0; ii < 4; ++ii)                          \
        _Pragma("unroll") for (int jj = 0; jj < 4; ++jj)                      \
            acc[(IOFF) + ii][jj] = __builtin_amdgcn_mfma_f32_16x16x32_f16(    \
                ah[ii], bf[jj], acc[(IOFF) + ii][jj], 0, 0, 0);               \
}
// One BK=32 tile: consume BUF, stage tile (via AS/BS) into SBUF.
#define TILE3(BUF, SBUF, AS, BS, DOST, VW) {                                  \
    if (DOST) ST_A3(SBUF, AS);                                                \
    RD_A3(BUF, 0); RD_B3(BUF);                                                \
    BAR; LGKM0; PRIO1; MM3(0); PRIO0; BAR;                                    \
    if (DOST) ST_B3(SBUF, BS);                                                \
    RD_A3(BUF, 1);                                                            \
    BAR; LGKM0; PRIO1; MM3(4); PRIO0; VW; BAR;                                \
}
// Virtual-K segment pointers: tile n in 0..47 (16 tiles per 512-K segment).
#define APTR(n) ((((n) >> 4) == 1 ? klo : khi) + arow0 + ((n) & 15) * 32)
#define BPTR(n) ((((n) >> 4) == 2 ? qlo : qhi) + brow0 + ((n) & 15) * 32)

__global__ __launch_bounds__(512, 2) void k_logits_8p(
    const _Float16* __restrict__ khi, const _Float16* __restrict__ klo,
    const _Float16* __restrict__ qhi, const _Float16* __restrict__ qlo,
    float* __restrict__ logits,       // [B][N][T]
    float* __restrict__ pval,         // [B][16][T]
    int*   __restrict__ pidx)         // [B][16][T]
{
    __shared__ __align__(16) _Float16 smem[65536];   // 128 KB: 4 ring buffers

    // Bijective XCD-aware swizzle of the flat block id (512 = 8 XCD x 64).
    const int f  = blockIdx.x + 8 * (blockIdx.y + 16 * blockIdx.z);
    const int fs = (f & 7) * 64 + (f >> 3);
    const int t0 = (fs & 7) * 256;
    const int by = (fs >> 3) & 15;
    const int b  = fs >> 7;
    const int n0 = by * 256;

    const int tid  = threadIdx.x;
    const int w    = tid >> 6;
    const int l    = tid & 63;
    const int quad = l >> 4;
    const int l15  = l & 15;
    const int wm   = (w >> 2) * 128;   // m (n-rows) offset; A-half = w>>2
    const int ha   = w >> 2;
    const int wn   = (w & 3) * 64;     // n (t-cols) offset

    const size_t arow0 = (size_t)n0 * CC;
    const size_t brow0 = ((size_t)b * TT + t0) * CC;

    // Staging: per-lane inverse-swizzled global source (LDS dest linear).
    // LDS chunk pc = r*512 + w*64 + l -> row = pc>>3, phys chunk = l&7,
    // logical chunk = (l&7)^(row&7); global row = (clog>>2)*128 + row.
    const int    lclog = (l & 7) ^ ((l >> 3) & 7);
    const size_t lsrc  = (size_t)(w * 8 + (l >> 3) + (lclog >> 2) * 128) * CC
                       + (size_t)(lclog & 3) * 8;

    // Swizzled ds_read bases (f16 units).
    const int cpxA    = ((ha << 2) | quad) ^ (l15 & 7);
    const int baseRdA = l15 * 64 + cpxA * 8;
    const int cpxB    = ((((w & 3) >> 1) << 2) | quad) ^ (l15 & 7);
    const int baseRdB = 8192 + (w & 1) * 4096 + l15 * 64 + cpxB * 8;

    f32x4 acc[8][4];
    #pragma unroll
    for (int i = 0; i < 8; ++i)
        #pragma unroll
        for (int j = 0; j < 4; ++j)
            acc[i][j] = (f32x4){0.f, 0.f, 0.f, 0.f};
    f16x8 ah[4];
    f16x8 bf[4];

    // Prologue: stage tiles 0,1,2 (12 loads); retire tile 0 (vmcnt 8).
    ST_A3(0, APTR(0)); ST_B3(0, BPTR(0));
    ST_A3(1, APTR(1)); ST_B3(1, BPTR(1));
    ST_A3(2, APTR(2)); ST_B3(2, BPTR(2));
    VMW(8); BAR;

    // Tiles 0..43: full pipeline (stage kt+3). Buffers static per group of 4.
    #pragma unroll 1
    for (int g = 0; g < 11; ++g) {
        const int kt = g * 4;
        { const int n_ = kt + 3; const _Float16* as_ = APTR(n_); const _Float16* bs_ = BPTR(n_);
          TILE3(0, 3, as_, bs_, 1, VMW(8)); }
        { const int n_ = kt + 4; const _Float16* as_ = APTR(n_); const _Float16* bs_ = BPTR(n_);
          TILE3(1, 0, as_, bs_, 1, VMW(8)); }
        { const int n_ = kt + 5; const _Float16* as_ = APTR(n_); const _Float16* bs_ = BPTR(n_);
          TILE3(2, 1, as_, bs_, 1, VMW(8)); }
        { const int n_ = kt + 6; const _Float16* as_ = APTR(n_); const _Float16* bs_ = BPTR(n_);
          TILE3(3, 2, as_, bs_, 1, VMW(8)); }
    }
    // Tile 44: stage tile 47. Tiles 45-47: drain.
    { const _Float16* as_ = APTR(47); const _Float16* bs_ = BPTR(47);
      TILE3(0, 3, as_, bs_, 1, VMW(8)); }
    TILE3(1, 0, khi, khi, 0, VMW(4));
    TILE3(2, 0, khi, khi, 0, VMW(0));
    TILE3(3, 0, khi, khi, 0, (void)0);

    // Epilogue: store logits (i-outer, j-inner).
    {
        const size_t lb = ((size_t)b * NN + n0 + wm) * TT + t0 + wn;
        #pragma unroll
        for (int i = 0; i < 8; ++i)
            #pragma unroll
            for (int r = 0; r < 4; ++r) {
                const size_t rowoff = lb + (size_t)(i * 16 + quad * 4 + r) * TT;
                #pragma unroll
                for (int j = 0; j < 4; ++j)
                    logits[rowoff + j * 16 + l15] = acc[i][j][r] * INV_SCALE2;
            }
    }
    // Partial argmax over this block's 256 n-rows (first-max tie-break).
    float bvj[4]; int bnj[4];
    #pragma unroll
    for (int j = 0; j < 4; ++j) {
        float bv = -3.0e38f; int bn = 0;
        #pragma unroll
        for (int i = 0; i < 8; ++i)
            #pragma unroll
            for (int r = 0; r < 4; ++r) {
                float v = acc[i][j][r] * INV_SCALE2;
                int row = n0 + wm + i * 16 + quad * 4 + r;
                if (v > bv) { bv = v; bn = row; }
            }
        #pragma unroll
        for (int m = 16; m <= 32; m <<= 1) {
            float ov = __shfl_xor(bv, m, 64);
            int   on = __shfl_xor(bn, m, 64);
            if (ov > bv || (ov == bv && on < bn)) { bv = ov; bn = on; }
        }
        bvj[j] = bv; bnj[j] = bn;
    }
    // Merge wave pairs (w, w+4): lower rows (w<4) win ties via strict >.
    float* rv = (float*)smem;
    int*   ri = (int*)(smem + 1024);
    __syncthreads();
    if (w >= 4 && l < 16) {
        #pragma unroll
        for (int j = 0; j < 4; ++j) {
            rv[wn + j * 16 + l] = bvj[j];
            ri[wn + j * 16 + l] = bnj[j];
        }
    }
    __syncthreads();
    if (w < 4 && l < 16) {
        #pragma unroll
        for (int j = 0; j < 4; ++j) {
            int cl = wn + j * 16 + l;
            float bv = bvj[j]; int bn = bnj[j];
            float ov = rv[cl];
            if (ov > bv) { bv = ov; bn = ri[cl]; }
            size_t o = ((size_t)b * 16 + by) * TT + t0 + cl;
            pval[o] = bv;
            pidx[o] = bn;
        }
    }
}

// ---------------------------------------------------------------------------
// Finalize: reduce 16 partial argmaxes per (b,t), gather z_q rows from vproj.
// ---------------------------------------------------------------------------
__global__ __launch_bounds__(256) void k_finalize(
    const float* __restrict__ pval,    // [B][16][T]
    const int*   __restrict__ pidx,    // [B][16][T]
    const float* __restrict__ vproj,   // [N][C]
    float* __restrict__ idx_out,       // [B][T] (float)
    float* __restrict__ zq)            // [B][C][T]
{
    const int b  = blockIdx.y;
    const int t0 = blockIdx.x * 32;
    const int tid = threadIdx.x;

    __shared__ int sfin[32];
    if (tid < 32) {
        const int t = t0 + tid;
        float bv = -3.0e38f; int bn = 0;
        #pragma unroll
        for (int k = 0; k < 16; ++k) {
            size_t o = ((size_t)b * 16 + k) * TT + t;
            float v = pval[o];
            if (v > bv) { bv = v; bn = pidx[o]; }
        }
        idx_out[(size_t)b * TT + t] = (float)bn;
        sfin[tid] = bn;
    }
    __syncthreads();
    for (int pos = tid; pos < 32 * CC; pos += 256) {
        int c = pos >> 5, tl = pos & 31;
        zq[((size_t)b * CC + c) * TT + t0 + tl] = vproj[(size_t)sfin[tl] * CC + c];
    }
}

// ---------------------------------------------------------------------------
extern "C" void kernel_launch(void* const* d_in, const int* in_sizes, int n_in,
                              void* d_out, int out_size, void* d_ws, size_t ws_size,
                              hipStream_t stream)
{
    (void)in_sizes; (void)n_in; (void)out_size; (void)ws_size;
    const float* hs = (const float*)d_in[0];
    const float* cb = (const float*)d_in[1];
    const float* Wq = (const float*)d_in[2];
    const float* bq = (const float*)d_in[3];
    const float* Wk = (const float*)d_in[4];
    const float* bk = (const float*)d_in[5];
    const float* Wv = (const float*)d_in[6];
    const float* bv = (const float*)d_in[7];
    const float* Wp = (const float*)d_in[8];
    const float* bp = (const float*)d_in[9];

    char* ws = (char*)d_ws;
    const size_t MB = 1024 * 1024;
    _Float16* hsTh = (_Float16*)(ws);              // [B*T][C] 8 MB
    _Float16* hsTl = (_Float16*)(ws + 8  * MB);
    _Float16* qhi  = (_Float16*)(ws + 16 * MB);    // [B*T][C] 8 MB
    _Float16* qlo  = (_Float16*)(ws + 24 * MB);
    _Float16* cbhi = (_Float16*)(ws + 32 * MB);    // [N][C]   4 MB
    _Float16* cblo = (_Float16*)(ws + 36 * MB);
    _Float16* khi  = (_Float16*)(ws + 40 * MB);    // [N][C]   4 MB
    _Float16* klo  = (_Float16*)(ws + 44 * MB);
    float*    vproj= (float*)   (ws + 48 * MB);    // [N][C]   8 MB fp32
    _Float16* wqTh = (_Float16*)(ws + 56 * MB);    // [C][C]   0.5 MB each
    _Float16* wqTl = (_Float16*)(ws + 56 * MB + 524288);
    _Float16* wkTh = (_Float16*)(ws + 57 * MB);
    _Float16* wkTl = (_Float16*)(ws + 57 * MB + 524288);
    _Float16* wvTh = (_Float16*)(ws + 58 * MB);
    _Float16* wvTl = (_Float16*)(ws + 58 * MB + 524288);
    // Partial argmax buffers alias the (dead-after-proj) cbhi region.
    float* pval = (float*)(ws + 32 * MB);          // [B][16][T] 512 KB
    int*   pidx = (int*)  (ws + 33 * MB);

    float* logits = (float*)d_out;                  // B*N*T
    float* idxf   = logits + (size_t)BB * NN * TT;  // B*T
    float* zq     = idxf + (size_t)BB * TT;         // B*C*T

    // Prep
    k_split<<<dim3((NN * CC / 4 + 255) / 256), 256, 0, stream>>>(
        cb, cbhi, cblo, NN * CC / 4);
    k_tsplit<<<dim3(TT / 64, CC / 64, BB), 256, 0, stream>>>(
        hs, hsTh, hsTl, (long)CC * TT, (long)TT * CC, TT, CC);
    k_tsplit_w<<<dim3(CC / 64, CC / 64, 3), 256, 0, stream>>>(
        Wq, Wk, Wv, wqTh, wkTh, wvTh, wqTl, wkTl, wvTl);

    // All projections in one dispatch (512 blocks -> 2 blocks/CU)
    k_proj_all<<<dim3(CC / 128, 64, 2), 256, 0, stream>>>(
        hsTh, hsTl, cbhi, cblo,
        wqTh, wqTl, wkTh, wkTl, wvTh, wvTl,
        bq, bk, bv, Wp, bp,
        qhi, qlo, khi, klo, vproj);

    // Logits: 256^2-tile 4-buffer-ring GEMM + fused partial argmax
    k_logits_8p<<<dim3(TT / 256, NN / 256, BB), 512, 0, stream>>>(
        khi, klo, qhi, qlo, logits, pval, pidx);

    // Final argmax reduce + gather
    k_finalize<<<dim3(TT / 32, BB), 256, 0, stream>>>(
        pval, pidx, vproj, idxf, zq);
}

// Round 6
// 332.606 us; speedup vs baseline: 1.0119x; 1.0097x over previous
//
#include <hip/hip_runtime.h>
#include <hip/hip_bf16.h>
#include <cstddef>
#include <cstdint>

// Problem constants
#define BB 4
#define CC 512
#define TT 2048
#define NN 4096
#define HH 4
// d = CC/HH = 128

constexpr float KFAC       = 0.04419417382415922f;           // 1/(sqrt(128)*2)
constexpr float INV_S18    = 1.0f / 262144.0f;               // 2^-18 (undo two x512)
constexpr float INV_SCALE2 = 1.0f / (512.0f * 512.0f);

typedef _Float16 f16x8 __attribute__((ext_vector_type(8)));
typedef _Float16 f16x4 __attribute__((ext_vector_type(4)));
typedef float    f32x4 __attribute__((ext_vector_type(4)));

__device__ __forceinline__ void gld16(const void* g, void* s) {
    __builtin_amdgcn_global_load_lds(
        (const __attribute__((address_space(1))) void*)g,
        (__attribute__((address_space(3))) void*)s, 16, 0, 0);
}

struct HL { _Float16 h, l; };
__device__ __forceinline__ HL split512(float x) {
    float v = x * 512.0f;
    _Float16 h = (_Float16)v;
    return { h, (_Float16)(v - (float)h) };
}

// ---------------------------------------------------------------------------
// Prep 1: elementwise split (x512) of cb [N][C] -> cbhi/cblo fp16 [N][C]
// ---------------------------------------------------------------------------
__global__ __launch_bounds__(256) void k_split(
    const float* __restrict__ src, _Float16* __restrict__ hi, _Float16* __restrict__ lo, int n4)
{
    int q = blockIdx.x * 256 + threadIdx.x;
    if (q >= n4) return;
    float4 v = *(const float4*)(src + (size_t)q * 4);
    f16x4 H, L;
    HL a = split512(v.x); H[0] = a.h; L[0] = a.l;
    HL b = split512(v.y); H[1] = b.h; L[1] = b.l;
    HL c = split512(v.z); H[2] = c.h; L[2] = c.l;
    HL d = split512(v.w); H[3] = d.h; L[3] = d.l;
    *(f16x4*)(hi + (size_t)q * 4) = H;
    *(f16x4*)(lo + (size_t)q * 4) = L;
}

// ---------------------------------------------------------------------------
// Prep 2: transpose + split (x512): src fp32 [R][S] -> dst hi/lo fp16 [S][R]
// ---------------------------------------------------------------------------
__device__ __forceinline__ void tsplit_body(
    const float* __restrict__ src, _Float16* __restrict__ hi, _Float16* __restrict__ lo,
    int S, int R, int r0, int s0)
{
    __shared__ float ls[64][65];
    const int tid = threadIdx.x;
    #pragma unroll
    for (int i = 0; i < 4; ++i) {
        int q = tid + i * 256;
        int row = q >> 4, c4 = (q & 15) * 4;
        float4 v = *(const float4*)(src + (size_t)(r0 + row) * S + s0 + c4);
        ls[row][c4] = v.x; ls[row][c4 + 1] = v.y;
        ls[row][c4 + 2] = v.z; ls[row][c4 + 3] = v.w;
    }
    __syncthreads();
    #pragma unroll
    for (int i = 0; i < 2; ++i) {
        int q = tid + i * 256;
        int orow = q >> 3, seg = (q & 7) * 8;
        f16x8 H, L;
        #pragma unroll
        for (int j = 0; j < 8; ++j) {
            HL s = split512(ls[seg + j][orow]);
            H[j] = s.h; L[j] = s.l;
        }
        size_t off = (size_t)(s0 + orow) * R + r0 + seg;
        *(f16x8*)(hi + off) = H;
        *(f16x8*)(lo + off) = L;
    }
}

__global__ __launch_bounds__(256) void k_tsplit(
    const float* __restrict__ src, _Float16* __restrict__ hi, _Float16* __restrict__ lo,
    long sbatch, long dbatch, int S, int R)
{
    src += (size_t)blockIdx.z * sbatch;
    hi  += (size_t)blockIdx.z * dbatch;
    lo  += (size_t)blockIdx.z * dbatch;
    tsplit_body(src, hi, lo, S, R, blockIdx.y * 64, blockIdx.x * 64);
}

__global__ __launch_bounds__(256) void k_tsplit_w(
    const float* __restrict__ w0, const float* __restrict__ w1, const float* __restrict__ w2,
    _Float16* __restrict__ h0, _Float16* __restrict__ h1, _Float16* __restrict__ h2,
    _Float16* __restrict__ l0, _Float16* __restrict__ l1, _Float16* __restrict__ l2)
{
    const int z = blockIdx.z;
    const float* src = z == 0 ? w0 : z == 1 ? w1 : w2;
    _Float16* hi = z == 0 ? h0 : z == 1 ? h1 : h2;
    _Float16* lo = z == 0 ? l0 : z == 1 ? l1 : l2;
    tsplit_body(src, hi, lo, CC, CC, blockIdx.y * 64, blockIdx.x * 64);
}

// ---------------------------------------------------------------------------
// MFMA tile core (projections): 128x128 tile, BK=32, 4 waves, 3-term split.
// ---------------------------------------------------------------------------
#define MFMA_TILE_DECLS                                                       \
    __shared__ __align__(16) _Float16 Ah[128][32];                            \
    __shared__ __align__(16) _Float16 Al[128][32];                            \
    __shared__ __align__(16) _Float16 Bh[128][32];                            \
    __shared__ __align__(16) _Float16 Bl[128][32];                            \
    const int tid  = threadIdx.x;                                             \
    const int w    = tid >> 6;                                                \
    const int l    = tid & 63;                                                \
    const int quad = l >> 4;                                                  \
    const int l15  = l & 15;                                                  \
    const int wm   = (w >> 1) * 64;                                           \
    const int wn   = (w & 1) * 64;                                            \
    const int rA   = l >> 2;                                                  \
    const int cA   = (l & 3) * 8;                                             \
    f32x4 acc[4][4];                                                          \
    _Pragma("unroll") for (int i = 0; i < 4; ++i)                             \
        _Pragma("unroll") for (int j = 0; j < 4; ++j)                         \
            acc[i][j] = (f32x4){0.f, 0.f, 0.f, 0.f};

#define MFMA_TILE_STAGE(pAh, pAl, pBh, pBl, k0, srcStride)                    \
    gld16(pAh + k0,                    &Ah[w * 32][0]);                       \
    gld16(pAh + k0 + 16 * (srcStride), &Ah[w * 32 + 16][0]);                  \
    gld16(pAl + k0,                    &Al[w * 32][0]);                       \
    gld16(pAl + k0 + 16 * (srcStride), &Al[w * 32 + 16][0]);                  \
    gld16(pBh + k0,                    &Bh[w * 32][0]);                       \
    gld16(pBh + k0 + 16 * (srcStride), &Bh[w * 32 + 16][0]);                  \
    gld16(pBl + k0,                    &Bl[w * 32][0]);                       \
    gld16(pBl + k0 + 16 * (srcStride), &Bl[w * 32 + 16][0]);

#define MFMA_TILE_COMPUTE                                                     \
    {                                                                         \
        f16x8 fah[4], fal[4], fbh[4], fbl[4];                                 \
        _Pragma("unroll") for (int i = 0; i < 4; ++i) {                       \
            fah[i] = *(const f16x8*)&Ah[wm + i * 16 + l15][quad * 8];         \
            fal[i] = *(const f16x8*)&Al[wm + i * 16 + l15][quad * 8];         \
            fbh[i] = *(const f16x8*)&Bh[wn + i * 16 + l15][quad * 8];         \
            fbl[i] = *(const f16x8*)&Bl[wn + i * 16 + l15][quad * 8];         \
        }                                                                     \
        _Pragma("unroll") for (int i = 0; i < 4; ++i)                         \
            _Pragma("unroll") for (int j = 0; j < 4; ++j) {                   \
                acc[i][j] = __builtin_amdgcn_mfma_f32_16x16x32_f16(fah[i], fbh[j], acc[i][j], 0, 0, 0); \
                acc[i][j] = __builtin_amdgcn_mfma_f32_16x16x32_f16(fah[i], fbl[j], acc[i][j], 0, 0, 0); \
                acc[i][j] = __builtin_amdgcn_mfma_f32_16x16x32_f16(fal[i], fbh[j], acc[i][j], 0, 0, 0); \
            }                                                                 \
    }

// ---------------------------------------------------------------------------
// Merged projections (512 blocks, 2 blocks/CU).
// z=0: q-proj + gate; z=1,y<32: k-proj split; z=1,y>=32: v-proj fp32.
// ---------------------------------------------------------------------------
__global__ __launch_bounds__(256, 2) void k_proj_all(
    const _Float16* __restrict__ hsTh, const _Float16* __restrict__ hsTl,
    const _Float16* __restrict__ cbhi, const _Float16* __restrict__ cblo,
    const _Float16* __restrict__ wqTh, const _Float16* __restrict__ wqTl,
    const _Float16* __restrict__ wkTh, const _Float16* __restrict__ wkTl,
    const _Float16* __restrict__ wvTh, const _Float16* __restrict__ wvTl,
    const float* __restrict__ bq, const float* __restrict__ bk, const float* __restrict__ bv,
    const float* __restrict__ Wp, const float* __restrict__ bp,
    _Float16* __restrict__ qhi, _Float16* __restrict__ qlo,
    _Float16* __restrict__ khi, _Float16* __restrict__ klo, float* __restrict__ vproj)
{
    const int z    = blockIdx.z;
    const int y    = blockIdx.y;
    const int c0   = blockIdx.x * 128;
    const int path = z == 0 ? 0 : (y < 32 ? 1 : 2);
    const int m0   = (z == 0 ? y : (y & 31)) * 128;
    const int hblk = c0 >> 7;

    const _Float16* srcAh = z == 0 ? hsTh : cbhi;
    const _Float16* srcAl = z == 0 ? hsTl : cblo;
    const _Float16* bTh   = path == 0 ? wqTh : path == 1 ? wkTh : wvTh;
    const _Float16* bTl   = path == 0 ? wqTl : path == 1 ? wkTl : wvTl;
    const float*    bias  = path == 0 ? bq   : path == 1 ? bk   : bv;

    MFMA_TILE_DECLS
    __shared__ float wp_sh[32];
    __shared__ float gate_sh[128];
    float gate = 0.f;

    const _Float16* pAh = srcAh + (size_t)(m0 + w * 32 + rA) * CC + cA;
    const _Float16* pAl = srcAl + (size_t)(m0 + w * 32 + rA) * CC + cA;
    const _Float16* pBh = bTh   + (size_t)(c0 + w * 32 + rA) * CC + cA;
    const _Float16* pBl = bTl   + (size_t)(c0 + w * 32 + rA) * CC + cA;

    for (int k0 = 0; k0 < CC; k0 += 32) {
        MFMA_TILE_STAGE(pAh, pAl, pBh, pBl, k0, CC)
        if (path == 0 && tid < 32) wp_sh[tid] = Wp[(size_t)(k0 + tid) * HH + hblk];
        __syncthreads();
        MFMA_TILE_COMPUTE
        if (path == 0 && tid < 128) {
            #pragma unroll
            for (int s = 0; s < 4; ++s) {
                f16x8 hv = *(const f16x8*)&Ah[tid][s * 8];
                f16x8 lv = *(const f16x8*)&Al[tid][s * 8];
                #pragma unroll
                for (int jj = 0; jj < 8; ++jj)
                    gate = fmaf((float)hv[jj] + (float)lv[jj], wp_sh[s * 8 + jj], gate);
            }
        }
        __syncthreads();
    }

    if (path == 0) {
        if (tid < 128)
            gate_sh[tid] = (gate * (1.0f / 512.0f) + bp[hblk]) * KFAC;
        __syncthreads();
        #pragma unroll
        for (int i = 0; i < 4; ++i)
            #pragma unroll
            for (int j = 0; j < 4; ++j) {
                int col = c0 + wn + j * 16 + l15;
                float bi = bias[col];
                #pragma unroll
                for (int r = 0; r < 4; ++r) {
                    int rloc = wm + i * 16 + quad * 4 + r;
                    float v = fmaf(acc[i][j][r], INV_S18, bi) * gate_sh[rloc];
                    HL s = split512(v);
                    qhi[(size_t)(m0 + rloc) * CC + col] = s.h;
                    qlo[(size_t)(m0 + rloc) * CC + col] = s.l;
                }
            }
    } else if (path == 1) {
        #pragma unroll
        for (int i = 0; i < 4; ++i)
            #pragma unroll
            for (int j = 0; j < 4; ++j) {
                int col = c0 + wn + j * 16 + l15;
                float bi = bias[col];
                #pragma unroll
                for (int r = 0; r < 4; ++r) {
                    int row = m0 + wm + i * 16 + quad * 4 + r;
                    float v = fmaf(acc[i][j][r], INV_S18, bi);
                    HL s = split512(v);
                    khi[(size_t)row * CC + col] = s.h;
                    klo[(size_t)row * CC + col] = s.l;
                }
            }
    } else {
        #pragma unroll
        for (int i = 0; i < 4; ++i)
            #pragma unroll
            for (int j = 0; j < 4; ++j) {
                int col = c0 + wn + j * 16 + l15;
                float bi = bias[col];
                #pragma unroll
                for (int r = 0; r < 4; ++r) {
                    int row = m0 + wm + i * 16 + quad * 4 + r;
                    vproj[(size_t)row * CC + col] = fmaf(acc[i][j][r], INV_S18, bi);
                }
            }
    }
}

// ---------------------------------------------------------------------------
// Logits: 256x256-tile GEMM over virtual K'=1536 (3-term split), BK=32,
// 4-buffer LDS ring, register-level software pipeline of the LDS reads
// (alternate register sets aE/aO, bb0/bb1; compiler emits COUNTED lgkmcnt so
// each phase's 6-read burst drains DURING the MFMA cluster).
// RACE FIX vs r5: vmcnt is PER-WAVE, so cross-wave LDS publication needs
// "every wave waits vmcnt, THEN barrier, THEN read". The counted VMW(4)
// now sits at the END of each tile (after MM_H(4), before the final BAR):
// it retires tile k+2's staging for this wave; the barrier publishes it;
// tile k+1's early reads of that buffer follow the barrier. Prologue
// likewise: stage 0,1,2; VMW(4) (retires tiles 0,1); BAR; pre-read tile 0.
// Ring: tile k stages k+3; steady-state 8 outstanding at tile end.
// Fused partial argmax over the 256 n-rows -> pval/pidx [B][16][T].
// ---------------------------------------------------------------------------
#define BAR   __builtin_amdgcn_s_barrier()
#define SB0   __builtin_amdgcn_sched_barrier(0)
#define PRIO1 __builtin_amdgcn_s_setprio(1)
#define PRIO0 __builtin_amdgcn_s_setprio(0)
#define VMW(N) asm volatile("s_waitcnt vmcnt(" #N ")" ::: "memory")

// Stage A (2 gld16/wave) / B of one BK=32 tile into ring buffer BUF.
#define ST_A3(BUF, SRC) {                                                     \
    gld16((SRC) + lsrc,           &smem[(BUF) * 16384 + w * 512]);            \
    gld16((SRC) + lsrc + 64 * CC, &smem[(BUF) * 16384 + 4096 + w * 512]);     \
}
#define ST_B3(BUF, SRC) {                                                     \
    gld16((SRC) + lsrc,           &smem[(BUF) * 16384 + 8192 + w * 512]);     \
    gld16((SRC) + lsrc + 64 * CC, &smem[(BUF) * 16384 + 12288 + w * 512]);    \
}
// Register-set reads. aE = A frags 0..3 (rows i*16, i<4), aO = frags 4..7.
#define RD_AE(BUF) {                                                          \
    _Pragma("unroll") for (int ii = 0; ii < 4; ++ii)                          \
        aE[ii] = *(const f16x8*)&smem[(BUF) * 16384 + ii * 1024 + baseRdA];   \
}
#define RD_AO(BUF) {                                                          \
    _Pragma("unroll") for (int ii = 0; ii < 4; ++ii)                          \
        aO[ii] = *(const f16x8*)&smem[(BUF) * 16384 + (4 + ii) * 1024 + baseRdA]; \
}
#define RD_BP(BUF, P, DST) {                                                  \
    DST[(P) * 2]     = *(const f16x8*)&smem[(BUF) * 16384 + baseRdB + ((P) * 2) * 1024];     \
    DST[(P) * 2 + 1] = *(const f16x8*)&smem[(BUF) * 16384 + baseRdB + ((P) * 2 + 1) * 1024]; \
}
#define MM_H(IOFF, A, B) {                                                    \
    _Pragma("unroll") for (int ii = 0; ii < 4; ++ii)                          \
        _Pragma("unroll") for (int jj = 0; jj < 4; ++jj)                      \
            acc[(IOFF) + ii][jj] = __builtin_amdgcn_mfma_f32_16x16x32_f16(    \
                (A)[ii], (B)[jj], acc[(IOFF) + ii][jj], 0, 0, 0);             \
}
// Tile k: consume BUF (regs pre-read during tile k-1), early-read tile k+1
// from NBUF (published by end-of-(k-1) VMW+BAR), stage tile k+3 into SBUF.
// VME at tile end retires tile k+2's loads (under MFMA cover), final BAR
// publishes them for tile k+1's early reads. CUR/NXT = B sets (parity of k).
#define TILE_P(BUF, NBUF, SBUF, AS, BS, CUR, NXT, DOST, VME) {                \
    RD_BP(NBUF, 0, NXT);                                                      \
    if (DOST) ST_A3(SBUF, AS);                                                \
    RD_AO(BUF);                                                               \
    SB0; BAR;                                                                 \
    PRIO1; MM_H(0, aE, CUR); PRIO0;                                           \
    BAR;                                                                      \
    if (DOST) ST_B3(SBUF, BS);                                                \
    RD_BP(NBUF, 1, NXT);                                                      \
    RD_AE(NBUF);                                                              \
    SB0; BAR;                                                                 \
    PRIO1; MM_H(4, aO, CUR); PRIO0;                                           \
    VME; BAR;                                                                 \
}
// Virtual-K segment pointers: tile n in 0..47 (16 tiles per 512-K segment).
#define APTR(n) ((((n) >> 4) == 1 ? klo : khi) + arow0 + ((n) & 15) * 32)
#define BPTR(n) ((((n) >> 4) == 2 ? qlo : qhi) + brow0 + ((n) & 15) * 32)

__global__ __launch_bounds__(512, 2) void k_logits_8p(
    const _Float16* __restrict__ khi, const _Float16* __restrict__ klo,
    const _Float16* __restrict__ qhi, const _Float16* __restrict__ qlo,
    float* __restrict__ logits,       // [B][N][T]
    float* __restrict__ pval,         // [B][16][T]
    int*   __restrict__ pidx)         // [B][16][T]
{
    __shared__ __align__(16) _Float16 smem[65536];   // 128 KB: 4 ring buffers

    // Bijective XCD-aware swizzle of the flat block id (512 = 8 XCD x 64).
    const int f  = blockIdx.x + 8 * (blockIdx.y + 16 * blockIdx.z);
    const int fs = (f & 7) * 64 + (f >> 3);
    const int t0 = (fs & 7) * 256;
    const int by = (fs >> 3) & 15;
    const int b  = fs >> 7;
    const int n0 = by * 256;

    const int tid  = threadIdx.x;
    const int w    = tid >> 6;
    const int l    = tid & 63;
    const int quad = l >> 4;
    const int l15  = l & 15;
    const int wm   = (w >> 2) * 128;   // m (n-rows) offset; A-half = w>>2
    const int ha   = w >> 2;
    const int wn   = (w & 3) * 64;     // n (t-cols) offset

    const size_t arow0 = (size_t)n0 * CC;
    const size_t brow0 = ((size_t)b * TT + t0) * CC;

    // Staging: per-lane inverse-swizzled global source (LDS dest linear).
    const int    lclog = (l & 7) ^ ((l >> 3) & 7);
    const size_t lsrc  = (size_t)(w * 8 + (l >> 3) + (lclog >> 2) * 128) * CC
                       + (size_t)(lclog & 3) * 8;

    // Swizzled ds_read bases (f16 units).
    const int cpxA    = ((ha << 2) | quad) ^ (l15 & 7);
    const int baseRdA = l15 * 64 + cpxA * 8;
    const int cpxB    = ((((w & 3) >> 1) << 2) | quad) ^ (l15 & 7);
    const int baseRdB = 8192 + (w & 1) * 4096 + l15 * 64 + cpxB * 8;

    f32x4 acc[8][4];
    #pragma unroll
    for (int i = 0; i < 8; ++i)
        #pragma unroll
        for (int j = 0; j < 4; ++j)
            acc[i][j] = (f32x4){0.f, 0.f, 0.f, 0.f};
    f16x8 aE[4], aO[4];    // A fragment sets (even rows 0..3 / odd 4..7)
    f16x8 bb0[4], bb1[4];  // B sets, parity of tile index

    // Prologue: stage tiles 0,1,2 (12 loads); EVERY wave retires tiles 0,1
    // (vmcnt(4)); barrier publishes; then pre-read tile 0 into registers.
    ST_A3(0, APTR(0)); ST_B3(0, BPTR(0));
    ST_A3(1, APTR(1)); ST_B3(1, BPTR(1));
    ST_A3(2, APTR(2)); ST_B3(2, BPTR(2));
    VMW(4); BAR;
    RD_AE(0); RD_BP(0, 0, bb0); RD_BP(0, 1, bb0);

    // Tiles 0..43 in groups of 4 (stage kt+3; buffers/parity compile-time).
    #pragma unroll 1
    for (int g = 0; g < 11; ++g) {
        const int kt = g * 4;
        { const _Float16* as_ = APTR(kt + 3); const _Float16* bs_ = BPTR(kt + 3);
          TILE_P(0, 1, 3, as_, bs_, bb0, bb1, 1, VMW(4)); }
        { const _Float16* as_ = APTR(kt + 4); const _Float16* bs_ = BPTR(kt + 4);
          TILE_P(1, 2, 0, as_, bs_, bb1, bb0, 1, VMW(4)); }
        { const _Float16* as_ = APTR(kt + 5); const _Float16* bs_ = BPTR(kt + 5);
          TILE_P(2, 3, 1, as_, bs_, bb0, bb1, 1, VMW(4)); }
        { const _Float16* as_ = APTR(kt + 6); const _Float16* bs_ = BPTR(kt + 6);
          TILE_P(3, 0, 2, as_, bs_, bb1, bb0, 1, VMW(4)); }
    }
    // Tile 44: stage tile 47; end-VMW(4) retires tile 46.
    { const _Float16* as_ = APTR(47); const _Float16* bs_ = BPTR(47);
      TILE_P(0, 1, 3, as_, bs_, bb0, bb1, 1, VMW(4)); }
    // Tile 45: no stage; end-VMW(0) retires tile 47 (last 4 outstanding).
    TILE_P(1, 2, 0, khi, khi, bb1, bb0, 0, VMW(0));
    // Tile 46: no stage; nothing outstanding.
    TILE_P(2, 3, 1, khi, khi, bb0, bb1, 0, (void)0);
    // Tile 47 (BUF 3, B set bb1): no next tile.
    RD_AO(3);
    SB0; BAR;
    PRIO1; MM_H(0, aE, bb1); PRIO0;
    BAR;
    PRIO1; MM_H(4, aO, bb1); PRIO0;

    // Epilogue: store logits (i-outer, j-inner).
    {
        const size_t lb = ((size_t)b * NN + n0 + wm) * TT + t0 + wn;
        #pragma unroll
        for (int i = 0; i < 8; ++i)
            #pragma unroll
            for (int r = 0; r < 4; ++r) {
                const size_t rowoff = lb + (size_t)(i * 16 + quad * 4 + r) * TT;
                #pragma unroll
                for (int j = 0; j < 4; ++j)
                    logits[rowoff + j * 16 + l15] = acc[i][j][r] * INV_SCALE2;
            }
    }
    // Partial argmax over this block's 256 n-rows (first-max tie-break).
    float bvj[4]; int bnj[4];
    #pragma unroll
    for (int j = 0; j < 4; ++j) {
        float bv = -3.0e38f; int bn = 0;
        #pragma unroll
        for (int i = 0; i < 8; ++i)
            #pragma unroll
            for (int r = 0; r < 4; ++r) {
                float v = acc[i][j][r] * INV_SCALE2;
                int row = n0 + wm + i * 16 + quad * 4 + r;
                if (v > bv) { bv = v; bn = row; }
            }
        #pragma unroll
        for (int m = 16; m <= 32; m <<= 1) {
            float ov = __shfl_xor(bv, m, 64);
            int   on = __shfl_xor(bn, m, 64);
            if (ov > bv || (ov == bv && on < bn)) { bv = ov; bn = on; }
        }
        bvj[j] = bv; bnj[j] = bn;
    }
    // Merge wave pairs (w, w+4): lower rows (w<4) win ties via strict >.
    float* rv = (float*)smem;
    int*   ri = (int*)(smem + 1024);
    __syncthreads();
    if (w >= 4 && l < 16) {
        #pragma unroll
        for (int j = 0; j < 4; ++j) {
            rv[wn + j * 16 + l] = bvj[j];
            ri[wn + j * 16 + l] = bnj[j];
        }
    }
    __syncthreads();
    if (w < 4 && l < 16) {
        #pragma unroll
        for (int j = 0; j < 4; ++j) {
            int cl = wn + j * 16 + l;
            float bv = bvj[j]; int bn = bnj[j];
            float ov = rv[cl];
            if (ov > bv) { bv = ov; bn = ri[cl]; }
            size_t o = ((size_t)b * 16 + by) * TT + t0 + cl;
            pval[o] = bv;
            pidx[o] = bn;
        }
    }
}

// ---------------------------------------------------------------------------
// Finalize: reduce 16 partial argmaxes per (b,t), gather z_q rows from vproj.
// ---------------------------------------------------------------------------
__global__ __launch_bounds__(256) void k_finalize(
    const float* __restrict__ pval,    // [B][16][T]
    const int*   __restrict__ pidx,    // [B][16][T]
    const float* __restrict__ vproj,   // [N][C]
    float* __restrict__ idx_out,       // [B][T] (float)
    float* __restrict__ zq)            // [B][C][T]
{
    const int b  = blockIdx.y;
    const int t0 = blockIdx.x * 32;
    const int tid = threadIdx.x;

    __shared__ int sfin[32];
    if (tid < 32) {
        const int t = t0 + tid;
        float bv = -3.0e38f; int bn = 0;
        #pragma unroll
        for (int k = 0; k < 16; ++k) {
            size_t o = ((size_t)b * 16 + k) * TT + t;
            float v = pval[o];
            if (v > bv) { bv = v; bn = pidx[o]; }
        }
        idx_out[(size_t)b * TT + t] = (float)bn;
        sfin[tid] = bn;
    }
    __syncthreads();
    for (int pos = tid; pos < 32 * CC; pos += 256) {
        int c = pos >> 5, tl = pos & 31;
        zq[((size_t)b * CC + c) * TT + t0 + tl] = vproj[(size_t)sfin[tl] * CC + c];
    }
}

// ---------------------------------------------------------------------------
extern "C" void kernel_launch(void* const* d_in, const int* in_sizes, int n_in,
                              void* d_out, int out_size, void* d_ws, size_t ws_size,
                              hipStream_t stream)
{
    (void)in_sizes; (void)n_in; (void)out_size; (void)ws_size;
    const float* hs = (const float*)d_in[0];
    const float* cb = (const float*)d_in[1];
    const float* Wq = (const float*)d_in[2];
    const float* bq = (const float*)d_in[3];
    const float* Wk = (const float*)d_in[4];
    const float* bk = (const float*)d_in[5];
    const float* Wv = (const float*)d_in[6];
    const float* bv = (const float*)d_in[7];
    const float* Wp = (const float*)d_in[8];
    const float* bp = (const float*)d_in[9];

    char* ws = (char*)d_ws;
    const size_t MB = 1024 * 1024;
    _Float16* hsTh = (_Float16*)(ws);              // [B*T][C] 8 MB
    _Float16* hsTl = (_Float16*)(ws + 8  * MB);
    _Float16* qhi  = (_Float16*)(ws + 16 * MB);    // [B*T][C] 8 MB
    _Float16* qlo  = (_Float16*)(ws + 24 * MB);
    _Float16* cbhi = (_Float16*)(ws + 32 * MB);    // [N][C]   4 MB
    _Float16* cblo = (_Float16*)(ws + 36 * MB);
    _Float16* khi  = (_Float16*)(ws + 40 * MB);    // [N][C]   4 MB
    _Float16* klo  = (_Float16*)(ws + 44 * MB);
    float*    vproj= (float*)   (ws + 48 * MB);    // [N][C]   8 MB fp32
    _Float16* wqTh = (_Float16*)(ws + 56 * MB);    // [C][C]   0.5 MB each
    _Float16* wqTl = (_Float16*)(ws + 56 * MB + 524288);
    _Float16* wkTh = (_Float16*)(ws + 57 * MB);
    _Float16* wkTl = (_Float16*)(ws + 57 * MB + 524288);
    _Float16* wvTh = (_Float16*)(ws + 58 * MB);
    _Float16* wvTl = (_Float16*)(ws + 58 * MB + 524288);
    // Partial argmax buffers alias the (dead-after-proj) cbhi region.
    float* pval = (float*)(ws + 32 * MB);          // [B][16][T] 512 KB
    int*   pidx = (int*)  (ws + 33 * MB);

    float* logits = (float*)d_out;                  // B*N*T
    float* idxf   = logits + (size_t)BB * NN * TT;  // B*T
    float* zq     = idxf + (size_t)BB * TT;         // B*C*T

    // Prep
    k_split<<<dim3((NN * CC / 4 + 255) / 256), 256, 0, stream>>>(
        cb, cbhi, cblo, NN * CC / 4);
    k_tsplit<<<dim3(TT / 64, CC / 64, BB), 256, 0, stream>>>(
        hs, hsTh, hsTl, (long)CC * TT, (long)TT * CC, TT, CC);
    k_tsplit_w<<<dim3(CC / 64, CC / 64, 3), 256, 0, stream>>>(
        Wq, Wk, Wv, wqTh, wkTh, wvTh, wqTl, wkTl, wvTl);

    // All projections in one dispatch (512 blocks -> 2 blocks/CU)
    k_proj_all<<<dim3(CC / 128, 64, 2), 256, 0, stream>>>(
        hsTh, hsTl, cbhi, cblo,
        wqTh, wqTl, wkTh, wkTl, wvTh, wvTl,
        bq, bk, bv, Wp, bp,
        qhi, qlo, khi, klo, vproj);

    // Logits: 256^2-tile register-pipelined ring GEMM + fused partial argmax
    k_logits_8p<<<dim3(TT / 256, NN / 256, BB), 512, 0, stream>>>(
        khi, klo, qhi, qlo, logits, pval, pidx);

    // Final argmax reduce + gather
    k_finalize<<<dim3(TT / 32, BB), 256, 0, stream>>>(
        pval, pidx, vproj, idxf, zq);
}

// Round 7
// 329.071 us; speedup vs baseline: 1.0228x; 1.0107x over previous
//
#include <hip/hip_runtime.h>
#include <hip/hip_bf16.h>
#include <cstddef>
#include <cstdint>

// Problem constants
#define BB 4
#define CC 512
#define TT 2048
#define NN 4096
#define HH 4
// d = CC/HH = 128

constexpr float KFAC       = 0.04419417382415922f;           // 1/(sqrt(128)*2)
constexpr float INV_S18    = 1.0f / 262144.0f;               // 2^-18 (undo two x512)
constexpr float INV_SCALE2 = 1.0f / (512.0f * 512.0f);

typedef _Float16 f16x8 __attribute__((ext_vector_type(8)));
typedef _Float16 f16x4 __attribute__((ext_vector_type(4)));
typedef float    f32x4 __attribute__((ext_vector_type(4)));

__device__ __forceinline__ void gld16(const void* g, void* s) {
    __builtin_amdgcn_global_load_lds(
        (const __attribute__((address_space(1))) void*)g,
        (__attribute__((address_space(3))) void*)s, 16, 0, 0);
}

struct HL { _Float16 h, l; };
__device__ __forceinline__ HL split512(float x) {
    float v = x * 512.0f;
    _Float16 h = (_Float16)v;
    return { h, (_Float16)(v - (float)h) };
}

// ---------------------------------------------------------------------------
// Transpose + split (x512) body: src fp32 [R][S] -> dst hi/lo fp16 [S][R],
// one 64x64 tile at (r0, s0).
// ---------------------------------------------------------------------------
__device__ __forceinline__ void tsplit_body(
    const float* __restrict__ src, _Float16* __restrict__ hi, _Float16* __restrict__ lo,
    int S, int R, int r0, int s0)
{
    __shared__ float ls[64][65];
    const int tid = threadIdx.x;
    #pragma unroll
    for (int i = 0; i < 4; ++i) {
        int q = tid + i * 256;
        int row = q >> 4, c4 = (q & 15) * 4;
        float4 v = *(const float4*)(src + (size_t)(r0 + row) * S + s0 + c4);
        ls[row][c4] = v.x; ls[row][c4 + 1] = v.y;
        ls[row][c4 + 2] = v.z; ls[row][c4 + 3] = v.w;
    }
    __syncthreads();
    #pragma unroll
    for (int i = 0; i < 2; ++i) {
        int q = tid + i * 256;
        int orow = q >> 3, seg = (q & 7) * 8;
        f16x8 H, L;
        #pragma unroll
        for (int j = 0; j < 8; ++j) {
            HL s = split512(ls[seg + j][orow]);
            H[j] = s.h; L[j] = s.l;
        }
        size_t off = (size_t)(s0 + orow) * R + r0 + seg;
        *(f16x8*)(hi + off) = H;
        *(f16x8*)(lo + off) = L;
    }
}

// ---------------------------------------------------------------------------
// Fused prep (one dispatch, 3264 blocks):
//   blocks [0,2048)      : elementwise split of cb [N][C] -> cbhi/cblo
//   blocks [2048,3072)   : hs per-batch transpose-split [C][T] -> [T][C]
//   blocks [3072,3264)   : Wq/Wk/Wv transpose-split [C][C] -> W^T hi/lo
// ---------------------------------------------------------------------------
__global__ __launch_bounds__(256) void k_prep(
    const float* __restrict__ cb,
    _Float16* __restrict__ cbhi, _Float16* __restrict__ cblo,
    const float* __restrict__ hs,
    _Float16* __restrict__ hsTh, _Float16* __restrict__ hsTl,
    const float* __restrict__ w0, const float* __restrict__ w1, const float* __restrict__ w2,
    _Float16* __restrict__ h0, _Float16* __restrict__ h1, _Float16* __restrict__ h2,
    _Float16* __restrict__ l0, _Float16* __restrict__ l1, _Float16* __restrict__ l2)
{
    const int bid = blockIdx.x;
    if (bid < 2048) {
        // cb elementwise split: q indexes float4 quads of [N][C]
        int q = bid * 256 + threadIdx.x;
        float4 v = *(const float4*)(cb + (size_t)q * 4);
        f16x4 H, L;
        HL a = split512(v.x); H[0] = a.h; L[0] = a.l;
        HL b = split512(v.y); H[1] = b.h; L[1] = b.l;
        HL c = split512(v.z); H[2] = c.h; L[2] = c.l;
        HL d = split512(v.w); H[3] = d.h; L[3] = d.l;
        *(f16x4*)(cbhi + (size_t)q * 4) = H;
        *(f16x4*)(cblo + (size_t)q * 4) = L;
    } else if (bid < 3072) {
        // hs transpose-split: x in [0,32) T-tiles, y in [0,8) C-tiles, z batch
        int b2 = bid - 2048;
        int x = b2 & 31, y = (b2 >> 5) & 7, z = b2 >> 8;
        const float* src = hs + (size_t)z * CC * TT;
        _Float16* hi = hsTh + (size_t)z * TT * CC;
        _Float16* lo = hsTl + (size_t)z * TT * CC;
        tsplit_body(src, hi, lo, TT, CC, y * 64, x * 64);
    } else {
        // weight transpose-split: x,y in [0,8), z in [0,3)
        int b3 = bid - 3072;
        int x = b3 & 7, y = (b3 >> 3) & 7, z = b3 >> 6;
        const float* src = z == 0 ? w0 : z == 1 ? w1 : w2;
        _Float16* hi = z == 0 ? h0 : z == 1 ? h1 : h2;
        _Float16* lo = z == 0 ? l0 : z == 1 ? l1 : l2;
        tsplit_body(src, hi, lo, CC, CC, y * 64, x * 64);
    }
}

// ---------------------------------------------------------------------------
// MFMA tile core (projections): 128x128 tile, BK=32, 4 waves, 3-term split.
// ---------------------------------------------------------------------------
#define MFMA_TILE_DECLS                                                       \
    __shared__ __align__(16) _Float16 Ah[128][32];                            \
    __shared__ __align__(16) _Float16 Al[128][32];                            \
    __shared__ __align__(16) _Float16 Bh[128][32];                            \
    __shared__ __align__(16) _Float16 Bl[128][32];                            \
    const int tid  = threadIdx.x;                                             \
    const int w    = tid >> 6;                                                \
    const int l    = tid & 63;                                                \
    const int quad = l >> 4;                                                  \
    const int l15  = l & 15;                                                  \
    const int wm   = (w >> 1) * 64;                                           \
    const int wn   = (w & 1) * 64;                                            \
    const int rA   = l >> 2;                                                  \
    const int cA   = (l & 3) * 8;                                             \
    f32x4 acc[4][4];                                                          \
    _Pragma("unroll") for (int i = 0; i < 4; ++i)                             \
        _Pragma("unroll") for (int j = 0; j < 4; ++j)                         \
            acc[i][j] = (f32x4){0.f, 0.f, 0.f, 0.f};

#define MFMA_TILE_STAGE(pAh, pAl, pBh, pBl, k0, srcStride)                    \
    gld16(pAh + k0,                    &Ah[w * 32][0]);                       \
    gld16(pAh + k0 + 16 * (srcStride), &Ah[w * 32 + 16][0]);                  \
    gld16(pAl + k0,                    &Al[w * 32][0]);                       \
    gld16(pAl + k0 + 16 * (srcStride), &Al[w * 32 + 16][0]);                  \
    gld16(pBh + k0,                    &Bh[w * 32][0]);                       \
    gld16(pBh + k0 + 16 * (srcStride), &Bh[w * 32 + 16][0]);                  \
    gld16(pBl + k0,                    &Bl[w * 32][0]);                       \
    gld16(pBl + k0 + 16 * (srcStride), &Bl[w * 32 + 16][0]);

#define MFMA_TILE_COMPUTE                                                     \
    {                                                                         \
        f16x8 fah[4], fal[4], fbh[4], fbl[4];                                 \
        _Pragma("unroll") for (int i = 0; i < 4; ++i) {                       \
            fah[i] = *(const f16x8*)&Ah[wm + i * 16 + l15][quad * 8];         \
            fal[i] = *(const f16x8*)&Al[wm + i * 16 + l15][quad * 8];         \
            fbh[i] = *(const f16x8*)&Bh[wn + i * 16 + l15][quad * 8];         \
            fbl[i] = *(const f16x8*)&Bl[wn + i * 16 + l15][quad * 8];         \
        }                                                                     \
        _Pragma("unroll") for (int i = 0; i < 4; ++i)                         \
            _Pragma("unroll") for (int j = 0; j < 4; ++j) {                   \
                acc[i][j] = __builtin_amdgcn_mfma_f32_16x16x32_f16(fah[i], fbh[j], acc[i][j], 0, 0, 0); \
                acc[i][j] = __builtin_amdgcn_mfma_f32_16x16x32_f16(fah[i], fbl[j], acc[i][j], 0, 0, 0); \
                acc[i][j] = __builtin_amdgcn_mfma_f32_16x16x32_f16(fal[i], fbh[j], acc[i][j], 0, 0, 0); \
            }                                                                 \
    }

// ---------------------------------------------------------------------------
// Merged projections (512 blocks, 2 blocks/CU).
// z=0: q-proj + gate; z=1,y<32: k-proj split; z=1,y>=32: v-proj fp32.
// ---------------------------------------------------------------------------
__global__ __launch_bounds__(256, 2) void k_proj_all(
    const _Float16* __restrict__ hsTh, const _Float16* __restrict__ hsTl,
    const _Float16* __restrict__ cbhi, const _Float16* __restrict__ cblo,
    const _Float16* __restrict__ wqTh, const _Float16* __restrict__ wqTl,
    const _Float16* __restrict__ wkTh, const _Float16* __restrict__ wkTl,
    const _Float16* __restrict__ wvTh, const _Float16* __restrict__ wvTl,
    const float* __restrict__ bq, const float* __restrict__ bk, const float* __restrict__ bv,
    const float* __restrict__ Wp, const float* __restrict__ bp,
    _Float16* __restrict__ qhi, _Float16* __restrict__ qlo,
    _Float16* __restrict__ khi, _Float16* __restrict__ klo, float* __restrict__ vproj)
{
    const int z    = blockIdx.z;
    const int y    = blockIdx.y;
    const int c0   = blockIdx.x * 128;
    const int path = z == 0 ? 0 : (y < 32 ? 1 : 2);
    const int m0   = (z == 0 ? y : (y & 31)) * 128;
    const int hblk = c0 >> 7;

    const _Float16* srcAh = z == 0 ? hsTh : cbhi;
    const _Float16* srcAl = z == 0 ? hsTl : cblo;
    const _Float16* bTh   = path == 0 ? wqTh : path == 1 ? wkTh : wvTh;
    const _Float16* bTl   = path == 0 ? wqTl : path == 1 ? wkTl : wvTl;
    const float*    bias  = path == 0 ? bq   : path == 1 ? bk   : bv;

    MFMA_TILE_DECLS
    __shared__ float wp_sh[32];
    __shared__ float gate_sh[128];
    float gate = 0.f;

    const _Float16* pAh = srcAh + (size_t)(m0 + w * 32 + rA) * CC + cA;
    const _Float16* pAl = srcAl + (size_t)(m0 + w * 32 + rA) * CC + cA;
    const _Float16* pBh = bTh   + (size_t)(c0 + w * 32 + rA) * CC + cA;
    const _Float16* pBl = bTl   + (size_t)(c0 + w * 32 + rA) * CC + cA;

    for (int k0 = 0; k0 < CC; k0 += 32) {
        MFMA_TILE_STAGE(pAh, pAl, pBh, pBl, k0, CC)
        if (path == 0 && tid < 32) wp_sh[tid] = Wp[(size_t)(k0 + tid) * HH + hblk];
        __syncthreads();
        MFMA_TILE_COMPUTE
        if (path == 0 && tid < 128) {
            #pragma unroll
            for (int s = 0; s < 4; ++s) {
                f16x8 hv = *(const f16x8*)&Ah[tid][s * 8];
                f16x8 lv = *(const f16x8*)&Al[tid][s * 8];
                #pragma unroll
                for (int jj = 0; jj < 8; ++jj)
                    gate = fmaf((float)hv[jj] + (float)lv[jj], wp_sh[s * 8 + jj], gate);
            }
        }
        __syncthreads();
    }

    if (path == 0) {
        if (tid < 128)
            gate_sh[tid] = (gate * (1.0f / 512.0f) + bp[hblk]) * KFAC;
        __syncthreads();
        #pragma unroll
        for (int i = 0; i < 4; ++i)
            #pragma unroll
            for (int j = 0; j < 4; ++j) {
                int col = c0 + wn + j * 16 + l15;
                float bi = bias[col];
                #pragma unroll
                for (int r = 0; r < 4; ++r) {
                    int rloc = wm + i * 16 + quad * 4 + r;
                    float v = fmaf(acc[i][j][r], INV_S18, bi) * gate_sh[rloc];
                    HL s = split512(v);
                    qhi[(size_t)(m0 + rloc) * CC + col] = s.h;
                    qlo[(size_t)(m0 + rloc) * CC + col] = s.l;
                }
            }
    } else if (path == 1) {
        #pragma unroll
        for (int i = 0; i < 4; ++i)
            #pragma unroll
            for (int j = 0; j < 4; ++j) {
                int col = c0 + wn + j * 16 + l15;
                float bi = bias[col];
                #pragma unroll
                for (int r = 0; r < 4; ++r) {
                    int row = m0 + wm + i * 16 + quad * 4 + r;
                    float v = fmaf(acc[i][j][r], INV_S18, bi);
                    HL s = split512(v);
                    khi[(size_t)row * CC + col] = s.h;
                    klo[(size_t)row * CC + col] = s.l;
                }
            }
    } else {
        #pragma unroll
        for (int i = 0; i < 4; ++i)
            #pragma unroll
            for (int j = 0; j < 4; ++j) {
                int col = c0 + wn + j * 16 + l15;
                float bi = bias[col];
                #pragma unroll
                for (int r = 0; r < 4; ++r) {
                    int row = m0 + wm + i * 16 + quad * 4 + r;
                    vproj[(size_t)row * CC + col] = fmaf(acc[i][j][r], INV_S18, bi);
                }
            }
    }
}

// ---------------------------------------------------------------------------
// Logits: 256x256-tile GEMM over virtual K'=1536 (3-term split), BK=32 with
// a 4-buffer LDS ring (4 x 32KB = 128KB): tile t+3 staged during tile t.
// Per tile: 2 phases x 16 MFMA; counted vmcnt(8) once per tile. 3-bit XOR
// swizzle (chunk^=(row&7), 16B granularity) as linear LDS dest +
// inverse-swizzled global source + swizzled ds_read -> 0 bank conflicts.
// (Round-4 verified structure — fastest variant of this family at ~114us.)
// Fused partial argmax over the 256 n-rows -> pval/pidx [B][16][T].
// ---------------------------------------------------------------------------
#define BAR   __builtin_amdgcn_s_barrier()
#define LGKM0 { asm volatile("s_waitcnt lgkmcnt(0)" ::: "memory"); __builtin_amdgcn_sched_barrier(0); }
#define PRIO1 __builtin_amdgcn_s_setprio(1)
#define PRIO0 __builtin_amdgcn_s_setprio(0)
#define VMW(N) asm volatile("s_waitcnt vmcnt(" #N ")" ::: "memory")

// Stage A (2 gld16/wave) / B of one BK=32 tile into ring buffer BUF.
#define ST_A3(BUF, SRC) {                                                     \
    gld16((SRC) + lsrc,           &smem[(BUF) * 16384 + w * 512]);            \
    gld16((SRC) + lsrc + 64 * CC, &smem[(BUF) * 16384 + 4096 + w * 512]);     \
}
#define ST_B3(BUF, SRC) {                                                     \
    gld16((SRC) + lsrc,           &smem[(BUF) * 16384 + 8192 + w * 512]);     \
    gld16((SRC) + lsrc + 64 * CC, &smem[(BUF) * 16384 + 12288 + w * 512]);    \
}
// Read 4 A row-frags (half H: frags H*4..H*4+3) / all 4 B col-frags.
#define RD_A3(BUF, H) {                                                       \
    _Pragma("unroll") for (int ii = 0; ii < 4; ++ii)                          \
        ah[ii] = *(const f16x8*)&smem[(BUF) * 16384 + ((H) * 4 + ii) * 1024 + baseRdA]; \
}
#define RD_B3(BUF) {                                                          \
    _Pragma("unroll") for (int jj = 0; jj < 4; ++jj)                          \
        bf[jj] = *(const f16x8*)&smem[(BUF) * 16384 + baseRdB + jj * 1024];   \
}
#define MM3(IOFF) {                                                           \
    _Pragma("unroll") for (int ii = 0; ii < 4; ++ii)                          \
        _Pragma("unroll") for (int jj = 0; jj < 4; ++jj)                      \
            acc[(IOFF) + ii][jj] = __builtin_amdgcn_mfma_f32_16x16x32_f16(    \
                ah[ii], bf[jj], acc[(IOFF) + ii][jj], 0, 0, 0);               \
}
// One BK=32 tile: consume BUF, stage tile (via AS/BS) into SBUF.
#define TILE3(BUF, SBUF, AS, BS, DOST, VW) {                                  \
    if (DOST) ST_A3(SBUF, AS);                                                \
    RD_A3(BUF, 0); RD_B3(BUF);                                                \
    BAR; LGKM0; PRIO1; MM3(0); PRIO0; BAR;                                    \
    if (DOST) ST_B3(SBUF, BS);                                                \
    RD_A3(BUF, 1);                                                            \
    BAR; LGKM0; PRIO1; MM3(4); PRIO0; VW; BAR;                                \
}
// Virtual-K segment pointers: tile n in 0..47 (16 tiles per 512-K segment).
#define APTR(n) ((((n) >> 4) == 1 ? klo : khi) + arow0 + ((n) & 15) * 32)
#define BPTR(n) ((((n) >> 4) == 2 ? qlo : qhi) + brow0 + ((n) & 15) * 32)

__global__ __launch_bounds__(512, 2) void k_logits_8p(
    const _Float16* __restrict__ khi, const _Float16* __restrict__ klo,
    const _Float16* __restrict__ qhi, const _Float16* __restrict__ qlo,
    float* __restrict__ logits,       // [B][N][T]
    float* __restrict__ pval,         // [B][16][T]
    int*   __restrict__ pidx)         // [B][16][T]
{
    __shared__ __align__(16) _Float16 smem[65536];   // 128 KB: 4 ring buffers

    // Bijective XCD-aware swizzle of the flat block id (512 = 8 XCD x 64).
    const int f  = blockIdx.x + 8 * (blockIdx.y + 16 * blockIdx.z);
    const int fs = (f & 7) * 64 + (f >> 3);
    const int t0 = (fs & 7) * 256;
    const int by = (fs >> 3) & 15;
    const int b  = fs >> 7;
    const int n0 = by * 256;

    const int tid  = threadIdx.x;
    const int w    = tid >> 6;
    const int l    = tid & 63;
    const int quad = l >> 4;
    const int l15  = l & 15;
    const int wm   = (w >> 2) * 128;   // m (n-rows) offset; A-half = w>>2
    const int ha   = w >> 2;
    const int wn   = (w & 3) * 64;     // n (t-cols) offset

    const size_t arow0 = (size_t)n0 * CC;
    const size_t brow0 = ((size_t)b * TT + t0) * CC;

    // Staging: per-lane inverse-swizzled global source (LDS dest linear).
    const int    lclog = (l & 7) ^ ((l >> 3) & 7);
    const size_t lsrc  = (size_t)(w * 8 + (l >> 3) + (lclog >> 2) * 128) * CC
                       + (size_t)(lclog & 3) * 8;

    // Swizzled ds_read bases (f16 units).
    const int cpxA    = ((ha << 2) | quad) ^ (l15 & 7);
    const int baseRdA = l15 * 64 + cpxA * 8;
    const int cpxB    = ((((w & 3) >> 1) << 2) | quad) ^ (l15 & 7);
    const int baseRdB = 8192 + (w & 1) * 4096 + l15 * 64 + cpxB * 8;

    f32x4 acc[8][4];
    #pragma unroll
    for (int i = 0; i < 8; ++i)
        #pragma unroll
        for (int j = 0; j < 4; ++j)
            acc[i][j] = (f32x4){0.f, 0.f, 0.f, 0.f};
    f16x8 ah[4];
    f16x8 bf[4];

    // Prologue: stage tiles 0,1,2 (12 loads); retire tile 0 (vmcnt 8).
    ST_A3(0, APTR(0)); ST_B3(0, BPTR(0));
    ST_A3(1, APTR(1)); ST_B3(1, BPTR(1));
    ST_A3(2, APTR(2)); ST_B3(2, BPTR(2));
    VMW(8); BAR;

    // Tiles 0..43: full pipeline (stage kt+3). Buffers static per group of 4.
    #pragma unroll 1
    for (int g = 0; g < 11; ++g) {
        const int kt = g * 4;
        { const int n_ = kt + 3; const _Float16* as_ = APTR(n_); const _Float16* bs_ = BPTR(n_);
          TILE3(0, 3, as_, bs_, 1, VMW(8)); }
        { const int n_ = kt + 4; const _Float16* as_ = APTR(n_); const _Float16* bs_ = BPTR(n_);
          TILE3(1, 0, as_, bs_, 1, VMW(8)); }
        { const int n_ = kt + 5; const _Float16* as_ = APTR(n_); const _Float16* bs_ = BPTR(n_);
          TILE3(2, 1, as_, bs_, 1, VMW(8)); }
        { const int n_ = kt + 6; const _Float16* as_ = APTR(n_); const _Float16* bs_ = BPTR(n_);
          TILE3(3, 2, as_, bs_, 1, VMW(8)); }
    }
    // Tile 44: stage tile 47. Tiles 45-47: drain.
    { const _Float16* as_ = APTR(47); const _Float16* bs_ = BPTR(47);
      TILE3(0, 3, as_, bs_, 1, VMW(8)); }
    TILE3(1, 0, khi, khi, 0, VMW(4));
    TILE3(2, 0, khi, khi, 0, VMW(0));
    TILE3(3, 0, khi, khi, 0, (void)0);

    // Epilogue: store logits (i-outer, j-inner).
    {
        const size_t lb = ((size_t)b * NN + n0 + wm) * TT + t0 + wn;
        #pragma unroll
        for (int i = 0; i < 8; ++i)
            #pragma unroll
            for (int r = 0; r < 4; ++r) {
                const size_t rowoff = lb + (size_t)(i * 16 + quad * 4 + r) * TT;
                #pragma unroll
                for (int j = 0; j < 4; ++j)
                    logits[rowoff + j * 16 + l15] = acc[i][j][r] * INV_SCALE2;
            }
    }
    // Partial argmax over this block's 256 n-rows (first-max tie-break).
    float bvj[4]; int bnj[4];
    #pragma unroll
    for (int j = 0; j < 4; ++j) {
        float bv = -3.0e38f; int bn = 0;
        #pragma unroll
        for (int i = 0; i < 8; ++i)
            #pragma unroll
            for (int r = 0; r < 4; ++r) {
                float v = acc[i][j][r] * INV_SCALE2;
                int row = n0 + wm + i * 16 + quad * 4 + r;
                if (v > bv) { bv = v; bn = row; }
            }
        #pragma unroll
        for (int m = 16; m <= 32; m <<= 1) {
            float ov = __shfl_xor(bv, m, 64);
            int   on = __shfl_xor(bn, m, 64);
            if (ov > bv || (ov == bv && on < bn)) { bv = ov; bn = on; }
        }
        bvj[j] = bv; bnj[j] = bn;
    }
    // Merge wave pairs (w, w+4): lower rows (w<4) win ties via strict >.
    float* rv = (float*)smem;
    int*   ri = (int*)(smem + 1024);
    __syncthreads();
    if (w >= 4 && l < 16) {
        #pragma unroll
        for (int j = 0; j < 4; ++j) {
            rv[wn + j * 16 + l] = bvj[j];
            ri[wn + j * 16 + l] = bnj[j];
        }
    }
    __syncthreads();
    if (w < 4 && l < 16) {
        #pragma unroll
        for (int j = 0; j < 4; ++j) {
            int cl = wn + j * 16 + l;
            float bv = bvj[j]; int bn = bnj[j];
            float ov = rv[cl];
            if (ov > bv) { bv = ov; bn = ri[cl]; }
            size_t o = ((size_t)b * 16 + by) * TT + t0 + cl;
            pval[o] = bv;
            pidx[o] = bn;
        }
    }
}

// ---------------------------------------------------------------------------
// Finalize: reduce 16 partial argmaxes per (b,t), gather z_q rows from vproj.
// ---------------------------------------------------------------------------
__global__ __launch_bounds__(256) void k_finalize(
    const float* __restrict__ pval,    // [B][16][T]
    const int*   __restrict__ pidx,    // [B][16][T]
    const float* __restrict__ vproj,   // [N][C]
    float* __restrict__ idx_out,       // [B][T] (float)
    float* __restrict__ zq)            // [B][C][T]
{
    const int b  = blockIdx.y;
    const int t0 = blockIdx.x * 32;
    const int tid = threadIdx.x;

    __shared__ int sfin[32];
    if (tid < 32) {
        const int t = t0 + tid;
        float bv = -3.0e38f; int bn = 0;
        #pragma unroll
        for (int k = 0; k < 16; ++k) {
            size_t o = ((size_t)b * 16 + k) * TT + t;
            float v = pval[o];
            if (v > bv) { bv = v; bn = pidx[o]; }
        }
        idx_out[(size_t)b * TT + t] = (float)bn;
        sfin[tid] = bn;
    }
    __syncthreads();
    for (int pos = tid; pos < 32 * CC; pos += 256) {
        int c = pos >> 5, tl = pos & 31;
        zq[((size_t)b * CC + c) * TT + t0 + tl] = vproj[(size_t)sfin[tl] * CC + c];
    }
}

// ---------------------------------------------------------------------------
extern "C" void kernel_launch(void* const* d_in, const int* in_sizes, int n_in,
                              void* d_out, int out_size, void* d_ws, size_t ws_size,
                              hipStream_t stream)
{
    (void)in_sizes; (void)n_in; (void)out_size; (void)ws_size;
    const float* hs = (const float*)d_in[0];
    const float* cb = (const float*)d_in[1];
    const float* Wq = (const float*)d_in[2];
    const float* bq = (const float*)d_in[3];
    const float* Wk = (const float*)d_in[4];
    const float* bk = (const float*)d_in[5];
    const float* Wv = (const float*)d_in[6];
    const float* bv = (const float*)d_in[7];
    const float* Wp = (const float*)d_in[8];
    const float* bp = (const float*)d_in[9];

    char* ws = (char*)d_ws;
    const size_t MB = 1024 * 1024;
    _Float16* hsTh = (_Float16*)(ws);              // [B*T][C] 8 MB
    _Float16* hsTl = (_Float16*)(ws + 8  * MB);
    _Float16* qhi  = (_Float16*)(ws + 16 * MB);    // [B*T][C] 8 MB
    _Float16* qlo  = (_Float16*)(ws + 24 * MB);
    _Float16* cbhi = (_Float16*)(ws + 32 * MB);    // [N][C]   4 MB
    _Float16* cblo = (_Float16*)(ws + 36 * MB);
    _Float16* khi  = (_Float16*)(ws + 40 * MB);    // [N][C]   4 MB
    _Float16* klo  = (_Float16*)(ws + 44 * MB);
    float*    vproj= (float*)   (ws + 48 * MB);    // [N][C]   8 MB fp32
    _Float16* wqTh = (_Float16*)(ws + 56 * MB);    // [C][C]   0.5 MB each
    _Float16* wqTl = (_Float16*)(ws + 56 * MB + 524288);
    _Float16* wkTh = (_Float16*)(ws + 57 * MB);
    _Float16* wkTl = (_Float16*)(ws + 57 * MB + 524288);
    _Float16* wvTh = (_Float16*)(ws + 58 * MB);
    _Float16* wvTl = (_Float16*)(ws + 58 * MB + 524288);
    // Partial argmax buffers alias the (dead-after-proj) cbhi region.
    float* pval = (float*)(ws + 32 * MB);          // [B][16][T] 512 KB
    int*   pidx = (int*)  (ws + 33 * MB);

    float* logits = (float*)d_out;                  // B*N*T
    float* idxf   = logits + (size_t)BB * NN * TT;  // B*T
    float* zq     = idxf + (size_t)BB * TT;         // B*C*T

    // Fused prep: cb split + hs transpose-split + weight transpose-split
    k_prep<<<dim3(3264), 256, 0, stream>>>(
        cb, cbhi, cblo,
        hs, hsTh, hsTl,
        Wq, Wk, Wv, wqTh, wkTh, wvTh, wqTl, wkTl, wvTl);

    // All projections in one dispatch (512 blocks -> 2 blocks/CU)
    k_proj_all<<<dim3(CC / 128, 64, 2), 256, 0, stream>>>(
        hsTh, hsTl, cbhi, cblo,
        wqTh, wqTl, wkTh, wkTl, wvTh, wvTl,
        bq, bk, bv, Wp, bp,
        qhi, qlo, khi, klo, vproj);

    // Logits: 256^2-tile 4-buffer-ring GEMM + fused partial argmax
    k_logits_8p<<<dim3(TT / 256, NN / 256, BB), 512, 0, stream>>>(
        khi, klo, qhi, qlo, logits, pval, pidx);

    // Final argmax reduce + gather
    k_finalize<<<dim3(TT / 32, BB), 256, 0, stream>>>(
        pval, pidx, vproj, idxf, zq);
}